// Round 3
// baseline (292.616 us; speedup 1.0000x reference)
//
#include <hip/hip_runtime.h>
#include <math.h>

#define H   20
#define H4  80
#define EPSF 1e-5f

__device__ __forceinline__ float sigm(float v) { return 1.0f / (1.0f + expf(-v)); }

// One LN-LSTM cell with zero initial hidden/cell state, LOW-REGISTER form.
//   gates = LN(in @ Wih^T, gi, bi) + bh          (LN(0)=bh exactly)
//   c     = sigmoid(i) * tanh(g)                 (f-gate dead: f*cx = 0)
//   out   = sigmoid(o) * tanh(LN(c, go, bo))
// Round-2 counters showed the a[80]-materializing version spills ~600 B/thread
// (WRITE_SIZE 39 MB) even at VGPR=140. This version never materializes a[80]:
//   pass A: Sa = sum(a), Sq = sum(a^2)   -> mu, sd (ddof=1 via Sq - Sa*mu)
//   pass B: recompute i/g pre-acts -> c[20]
//   pass C: recompute o pre-acts   -> out[20]
// 1.75x matvec FLOPs, but live set ~70 floats -> no scratch.
__device__ __forceinline__ void lstm_layer_lowreg(
    const float in[H], float out[H],
    const float* __restrict__ Wih, const float* __restrict__ gi,
    const float* __restrict__ bi,  const float* __restrict__ bh,
    const float* __restrict__ go,  const float* __restrict__ bo)
{
    // pass A: moments of the 80 gate pre-activations
    float Sa = 0.f, Sq = 0.f;
    for (int j = 0; j < H4; ++j) {
        float acc = 0.f;
        #pragma unroll
        for (int h = 0; h < H; ++h)
            acc = fmaf(Wih[j * H + h], in[h], acc);
        Sa += acc;
        Sq = fmaf(acc, acc, Sq);
    }
    float mu  = Sa * (1.0f / H4);
    float var = fmaxf((Sq - Sa * mu) * (1.0f / (H4 - 1)), 0.f);  // ddof=1
    float inv = 1.0f / (sqrtf(var) + EPSF);

    // pass B: i (rows 0..19) and g (rows 60..79) gates -> c
    float c[H];
    float Sc = 0.f;
    for (int h = 0; h < H; ++h) {
        float ai = 0.f, ag = 0.f;
        #pragma unroll
        for (int k = 0; k < H; ++k) {
            ai = fmaf(Wih[h * H + k],        in[k], ai);
            ag = fmaf(Wih[(60 + h) * H + k], in[k], ag);
        }
        float gv_i = fmaf((ai - mu) * inv, gi[h],      bi[h])      + bh[h];
        float gv_g = fmaf((ag - mu) * inv, gi[60 + h], bi[60 + h]) + bh[60 + h];
        c[h] = sigm(gv_i) * tanhf(gv_g);
        Sc += c[h];
    }
    float mu2 = Sc * (1.0f / H);
    float var2 = 0.f;
    #pragma unroll
    for (int h = 0; h < H; ++h) { float d = c[h] - mu2; var2 = fmaf(d, d, var2); }
    float inv2 = 1.0f / (sqrtf(var2 * (1.0f / (H - 1))) + EPSF);

    // pass C: o (rows 40..59) gates -> out
    for (int h = 0; h < H; ++h) {
        float ao = 0.f;
        #pragma unroll
        for (int k = 0; k < H; ++k)
            ao = fmaf(Wih[(40 + h) * H + k], in[k], ao);
        float gv_o = fmaf((ao - mu) * inv, gi[40 + h], bi[40 + h]) + bh[40 + h];
        out[h] = sigm(gv_o) * tanhf((c[h] - mu2) * inv2 * go[h] + bo[h]);
    }
}

__device__ float eval_net(
    float x,
    const float* __restrict__ W1,   const float* __restrict__ b1,
    const float* __restrict__ g1,   const float* __restrict__ be1,
    const float* __restrict__ Wih0, const float* __restrict__ gi0,
    const float* __restrict__ bi0,  const float* __restrict__ bh0,
    const float* __restrict__ go0,  const float* __restrict__ bo0,
    const float* __restrict__ Wih1, const float* __restrict__ gi1,
    const float* __restrict__ bi1,  const float* __restrict__ bh1,
    const float* __restrict__ go1,  const float* __restrict__ bo1,
    const float* __restrict__ Wout, const float* __restrict__ bout)
{
    float cur[H];
    {   // stage 1: LN(x*W1 + b1) -> tanh   (classic two-pass, only 20 live)
        float t[H];
        float mu = 0.f;
        #pragma unroll
        for (int h = 0; h < H; ++h) { t[h] = fmaf(x, W1[h], b1[h]); mu += t[h]; }
        mu *= (1.0f / H);
        float var = 0.f;
        #pragma unroll
        for (int h = 0; h < H; ++h) { float d = t[h] - mu; var = fmaf(d, d, var); }
        float sd  = sqrtf(var * (1.0f / (H - 1)));
        float inv = 1.0f / (sd + EPSF);
        #pragma unroll
        for (int h = 0; h < H; ++h)
            cur[h] = tanhf((t[h] - mu) * inv * g1[h] + be1[h]);
    }
    float nxt[H];
    lstm_layer_lowreg(cur, nxt, Wih0, gi0, bi0, bh0, go0, bo0);
    lstm_layer_lowreg(nxt, cur, Wih1, gi1, bi1, bh1, go1, bo1);

    float r = bout[0];
    #pragma unroll
    for (int h = 0; h < H; ++h) r = fmaf(cur[h], Wout[h], r);
    return r;
}

#define EVAL_ARGS W1, b1, g1, be1, Wih0, gi0, bi0, bh0, go0, bo0, \
                  Wih1, gi1, bi1, bh1, go1, bo1, Wout, bout
#define EVAL_PARAMS \
    const float* __restrict__ W1,   const float* __restrict__ b1,   \
    const float* __restrict__ g1,   const float* __restrict__ be1,  \
    const float* __restrict__ Wih0, const float* __restrict__ gi0,  \
    const float* __restrict__ bi0,  const float* __restrict__ bh0,  \
    const float* __restrict__ go0,  const float* __restrict__ bo0,  \
    const float* __restrict__ Wih1, const float* __restrict__ gi1,  \
    const float* __restrict__ bi1,  const float* __restrict__ bh1,  \
    const float* __restrict__ go1,  const float* __restrict__ gof1, \
    const float* __restrict__ Wout, const float* __restrict__ bout

// Build the PAIRED table directly: thread i computes F_i and writes
//   tab2[i].x   = F_i   (i < ntab)
//   tab2[i-1].y = F_i   (i > 0)
// Each float written exactly once -> no race; pack kernel eliminated.
__global__ void __launch_bounds__(256, 1)
build_tab2_kernel(float2* __restrict__ tab2, int ntab,
                  float lo, float hstep, EVAL_PARAMS)
{
    const float* bo1 = gof1;  // macro param naming
    int i = blockIdx.x * blockDim.x + threadIdx.x;
    if (i <= ntab) {
        float v = eval_net(lo + hstep * (float)i, EVAL_ARGS);
        if (i < ntab) tab2[i].x     = v;
        if (i > 0)    tab2[i - 1].y = v;
    }
}

// Scalar-table builder (fallback path).
__global__ void __launch_bounds__(256, 1)
build_tab_kernel(float* __restrict__ tab, int ntab,
                 float lo, float hstep, EVAL_PARAMS)
{
    const float* bo1 = gof1;
    int i = blockIdx.x * blockDim.x + threadIdx.x;
    if (i <= ntab)
        tab[i] = eval_net(lo + hstep * (float)i, EVAL_ARGS);
}

// out[i] = lerp over tab2 at clamp(x[i])
__global__ void __launch_bounds__(256)
lookup_kernel(const float* __restrict__ x, float* __restrict__ out,
              const float2* __restrict__ tab2, int n,
              float lo, float hi, float inv_h, int ntab)
{
    int i4 = blockIdx.x * blockDim.x + threadIdx.x;
    int base = i4 * 4;
    if (base + 3 < n) {
        float4 v = *reinterpret_cast<const float4*>(x + base);
        float r[4];
        float xs[4] = {v.x, v.y, v.z, v.w};
        #pragma unroll
        for (int k = 0; k < 4; ++k) {
            float xx = fminf(fmaxf(xs[k], lo), hi);
            float tt = (xx - lo) * inv_h;
            int idx  = (int)tt;
            idx = idx < (ntab - 1) ? idx : (ntab - 1);
            float fr = tt - (float)idx;
            float2 p = tab2[idx];
            r[k] = fmaf(fr, p.y - p.x, p.x);
        }
        float4 o = make_float4(r[0], r[1], r[2], r[3]);
        *reinterpret_cast<float4*>(out + base) = o;
    } else {
        for (int k = 0; k < 4; ++k) {
            int idx_e = base + k;
            if (idx_e < n) {
                float xx = fminf(fmaxf(x[idx_e], lo), hi);
                float tt = (xx - lo) * inv_h;
                int idx  = (int)tt;
                idx = idx < (ntab - 1) ? idx : (ntab - 1);
                float fr = tt - (float)idx;
                float2 p = tab2[idx];
                out[idx_e] = fmaf(fr, p.y - p.x, p.x);
            }
        }
    }
}

// Scalar-table lookup (fallback when ws can't hold the paired table).
__global__ void __launch_bounds__(256)
lookup_kernel_scalar(const float* __restrict__ x, float* __restrict__ out,
                     const float* __restrict__ tab, int n,
                     float lo, float hi, float inv_h, int ntab)
{
    int i4 = blockIdx.x * blockDim.x + threadIdx.x;
    int base = i4 * 4;
    for (int k = 0; k < 4; ++k) {
        int idx_e = base + k;
        if (idx_e < n) {
            float xx = fminf(fmaxf(x[idx_e], lo), hi);
            float tt = (xx - lo) * inv_h;
            int idx  = (int)tt;
            idx = idx < (ntab - 1) ? idx : (ntab - 1);
            float fr = tt - (float)idx;
            out[idx_e] = fmaf(fr, tab[idx + 1] - tab[idx], tab[idx]);
        }
    }
}

// Correct-but-slow fallback if workspace can't hold any table.
__global__ void __launch_bounds__(256, 1)
direct_kernel(const float* __restrict__ x, float* __restrict__ out,
              int n, EVAL_PARAMS)
{
    const float* bo1 = gof1;
    int i = blockIdx.x * blockDim.x + threadIdx.x;
    if (i < n)
        out[i] = eval_net(x[i], EVAL_ARGS);
}

extern "C" void kernel_launch(void* const* d_in, const int* in_sizes, int n_in,
                              void* d_out, int out_size, void* d_ws, size_t ws_size,
                              hipStream_t stream) {
    const float* x    = (const float*)d_in[0];
    const float* W1   = (const float*)d_in[1];
    const float* b1   = (const float*)d_in[2];
    const float* g1   = (const float*)d_in[3];
    const float* be1  = (const float*)d_in[4];
    const float* Wih0 = (const float*)d_in[5];
    // d_in[6] = Whh0 (dead: hx==0)
    const float* gi0  = (const float*)d_in[7];
    const float* bi0  = (const float*)d_in[8];
    // d_in[9] = gh0 (dead)
    const float* bh0  = (const float*)d_in[10];
    const float* go0  = (const float*)d_in[11];
    const float* bo0  = (const float*)d_in[12];
    const float* Wih1 = (const float*)d_in[13];
    // d_in[14] = Whh1 (dead)
    const float* gi1  = (const float*)d_in[15];
    const float* bi1  = (const float*)d_in[16];
    // d_in[17] = gh1 (dead)
    const float* bh1  = (const float*)d_in[18];
    const float* go1  = (const float*)d_in[19];
    const float* bo1  = (const float*)d_in[20];
    const float* Wout = (const float*)d_in[21];
    const float* bout = (const float*)d_in[22];

    float* out = (float*)d_out;
    int n = in_sizes[0];

    const int   NTAB = 65536;
    const float LO   = -8.0f, HIv = 8.0f;
    const float hstep = (HIv - LO) / (float)NTAB;

    const size_t pair_bytes = (size_t)NTAB * sizeof(float2);        // 512 KB
    const size_t tmp_bytes  = (size_t)(NTAB + 1) * sizeof(float);   // 256 KB

    if (ws_size >= pair_bytes) {
        float2* tab2 = (float2*)d_ws;
        int bblocks = (NTAB + 1 + 255) / 256;
        build_tab2_kernel<<<bblocks, 256, 0, stream>>>(tab2, NTAB, LO, hstep, EVAL_ARGS);
        int lblocks = ((n + 3) / 4 + 255) / 256;
        lookup_kernel<<<lblocks, 256, 0, stream>>>(x, out, tab2, n, LO, HIv,
                                                   1.0f / hstep, NTAB);
    } else if (ws_size >= tmp_bytes) {
        float* tab = (float*)d_ws;
        int bblocks = (NTAB + 1 + 255) / 256;
        build_tab_kernel<<<bblocks, 256, 0, stream>>>(tab, NTAB, LO, hstep, EVAL_ARGS);
        int lblocks = ((n + 3) / 4 + 255) / 256;
        lookup_kernel_scalar<<<lblocks, 256, 0, stream>>>(x, out, tab, n, LO, HIv,
                                                          1.0f / hstep, NTAB);
    } else {
        int blocks = (n + 255) / 256;
        direct_kernel<<<blocks, 256, 0, stream>>>(x, out, n, EVAL_ARGS);
    }
}

// Round 4
// 242.495 us; speedup vs baseline: 1.2067x; 1.2067x over previous
//
#include <hip/hip_runtime.h>
#include <math.h>

#define H   20
#define H4  80
#define EPSF 1e-5f

__device__ __forceinline__ float sigm(float v) { return 1.0f / (1.0f + expf(-v)); }

// One LN-LSTM cell with zero initial hidden/cell state:
//   gates = LN(in @ Wih^T, gi, bi) + bh          (LN(0)=bh exactly)
//   c     = sigmoid(i) * tanh(g)                 (f-gate dead: f*cx = 0)
//   out   = sigmoid(o) * tanh(LN(c, go, bo))
//
// CRITICAL (rounds 1-3 post-mortem): every loop that indexes a thread-local
// array is FULLY unrolled. Partial unroll (`#pragma unroll 4`) or no unroll
// leaves a runtime index -> hipcc allocates the array in scratch (rule #20),
// which showed up as 39-98 MB of WRITE_SIZE and 150-215 us builder time.
__device__ __forceinline__ void lstm_layer(
    const float in[H], float out[H],
    const float* __restrict__ Wih, const float* __restrict__ gi,
    const float* __restrict__ bi,  const float* __restrict__ bh,
    const float* __restrict__ go,  const float* __restrict__ bo)
{
    float a[H4];
    float mu = 0.f;
    #pragma unroll
    for (int j = 0; j < H4; ++j) {
        float acc = 0.f;
        #pragma unroll
        for (int h = 0; h < H; ++h)
            acc = fmaf(Wih[j * H + h], in[h], acc);
        a[j] = acc;
        mu += acc;
    }
    mu *= (1.0f / H4);
    float var = 0.f;
    #pragma unroll
    for (int j = 0; j < H4; ++j) { float d = a[j] - mu; var = fmaf(d, d, var); }
    float sd  = sqrtf(var * (1.0f / (H4 - 1)));   // ddof=1
    float inv = 1.0f / (sd + EPSF);

    float c[H];
    float mu2 = 0.f;
    #pragma unroll
    for (int h = 0; h < H; ++h) {
        float gv_i = fmaf((a[h]      - mu) * inv, gi[h],      bi[h])      + bh[h];
        float gv_g = fmaf((a[60 + h] - mu) * inv, gi[60 + h], bi[60 + h]) + bh[60 + h];
        c[h] = sigm(gv_i) * tanhf(gv_g);
        mu2 += c[h];
    }
    mu2 *= (1.0f / H);
    float var2 = 0.f;
    #pragma unroll
    for (int h = 0; h < H; ++h) { float d = c[h] - mu2; var2 = fmaf(d, d, var2); }
    float sd2  = sqrtf(var2 * (1.0f / (H - 1)));
    float inv2 = 1.0f / (sd2 + EPSF);

    #pragma unroll
    for (int h = 0; h < H; ++h) {
        float gv_o = fmaf((a[40 + h] - mu) * inv, gi[40 + h], bi[40 + h]) + bh[40 + h];
        out[h] = sigm(gv_o) * tanhf((c[h] - mu2) * inv2 * go[h] + bo[h]);
    }
}

__device__ float eval_net(
    float x,
    const float* __restrict__ W1,   const float* __restrict__ b1,
    const float* __restrict__ g1,   const float* __restrict__ be1,
    const float* __restrict__ Wih0, const float* __restrict__ gi0,
    const float* __restrict__ bi0,  const float* __restrict__ bh0,
    const float* __restrict__ go0,  const float* __restrict__ bo0,
    const float* __restrict__ Wih1, const float* __restrict__ gi1,
    const float* __restrict__ bi1,  const float* __restrict__ bh1,
    const float* __restrict__ go1,  const float* __restrict__ bo1,
    const float* __restrict__ Wout, const float* __restrict__ bout)
{
    float cur[H];
    {   // stage 1: LN(x*W1 + b1) -> tanh
        float t[H];
        float mu = 0.f;
        #pragma unroll
        for (int h = 0; h < H; ++h) { t[h] = fmaf(x, W1[h], b1[h]); mu += t[h]; }
        mu *= (1.0f / H);
        float var = 0.f;
        #pragma unroll
        for (int h = 0; h < H; ++h) { float d = t[h] - mu; var = fmaf(d, d, var); }
        float sd  = sqrtf(var * (1.0f / (H - 1)));
        float inv = 1.0f / (sd + EPSF);
        #pragma unroll
        for (int h = 0; h < H; ++h)
            cur[h] = tanhf((t[h] - mu) * inv * g1[h] + be1[h]);
    }
    float nxt[H];
    lstm_layer(cur, nxt, Wih0, gi0, bi0, bh0, go0, bo0);
    lstm_layer(nxt, cur, Wih1, gi1, bi1, bh1, go1, bo1);

    float r = bout[0];
    #pragma unroll
    for (int h = 0; h < H; ++h) r = fmaf(cur[h], Wout[h], r);
    return r;
}

#define EVAL_ARGS W1, b1, g1, be1, Wih0, gi0, bi0, bh0, go0, bo0, \
                  Wih1, gi1, bi1, bh1, go1, bo1, Wout, bout
#define EVAL_PARAMS \
    const float* __restrict__ W1,   const float* __restrict__ b1,   \
    const float* __restrict__ g1,   const float* __restrict__ be1,  \
    const float* __restrict__ Wih0, const float* __restrict__ gi0,  \
    const float* __restrict__ bi0,  const float* __restrict__ bh0,  \
    const float* __restrict__ go0,  const float* __restrict__ bo0,  \
    const float* __restrict__ Wih1, const float* __restrict__ gi1,  \
    const float* __restrict__ bi1,  const float* __restrict__ bh1,  \
    const float* __restrict__ go1,  const float* __restrict__ gof1, \
    const float* __restrict__ Wout, const float* __restrict__ bout

// Build the PAIRED table directly: thread i computes F_i and writes
//   tab2[i].x   = F_i   (i < ntab)
//   tab2[i-1].y = F_i   (i > 0)
// Each float written exactly once -> no race.
__global__ void __launch_bounds__(256, 1)
build_tab2_kernel(float2* __restrict__ tab2, int ntab,
                  float lo, float hstep, EVAL_PARAMS)
{
    const float* bo1 = gof1;  // macro param naming
    int i = blockIdx.x * blockDim.x + threadIdx.x;
    if (i <= ntab) {
        float v = eval_net(lo + hstep * (float)i, EVAL_ARGS);
        if (i < ntab) tab2[i].x     = v;
        if (i > 0)    tab2[i - 1].y = v;
    }
}

// Scalar-table builder (fallback path).
__global__ void __launch_bounds__(256, 1)
build_tab_kernel(float* __restrict__ tab, int ntab,
                 float lo, float hstep, EVAL_PARAMS)
{
    const float* bo1 = gof1;
    int i = blockIdx.x * blockDim.x + threadIdx.x;
    if (i <= ntab)
        tab[i] = eval_net(lo + hstep * (float)i, EVAL_ARGS);
}

// out[i] = lerp over tab2 at clamp(x[i])
__global__ void __launch_bounds__(256)
lookup_kernel(const float* __restrict__ x, float* __restrict__ out,
              const float2* __restrict__ tab2, int n,
              float lo, float hi, float inv_h, int ntab)
{
    int i4 = blockIdx.x * blockDim.x + threadIdx.x;
    int base = i4 * 4;
    if (base + 3 < n) {
        float4 v = *reinterpret_cast<const float4*>(x + base);
        float r[4];
        float xs[4] = {v.x, v.y, v.z, v.w};
        #pragma unroll
        for (int k = 0; k < 4; ++k) {
            float xx = fminf(fmaxf(xs[k], lo), hi);
            float tt = (xx - lo) * inv_h;
            int idx  = (int)tt;
            idx = idx < (ntab - 1) ? idx : (ntab - 1);
            float fr = tt - (float)idx;
            float2 p = tab2[idx];
            r[k] = fmaf(fr, p.y - p.x, p.x);
        }
        float4 o = make_float4(r[0], r[1], r[2], r[3]);
        *reinterpret_cast<float4*>(out + base) = o;
    } else {
        for (int k = 0; k < 4; ++k) {
            int idx_e = base + k;
            if (idx_e < n) {
                float xx = fminf(fmaxf(x[idx_e], lo), hi);
                float tt = (xx - lo) * inv_h;
                int idx  = (int)tt;
                idx = idx < (ntab - 1) ? idx : (ntab - 1);
                float fr = tt - (float)idx;
                float2 p = tab2[idx];
                out[idx_e] = fmaf(fr, p.y - p.x, p.x);
            }
        }
    }
}

// Scalar-table lookup (fallback when ws can't hold the paired table).
__global__ void __launch_bounds__(256)
lookup_kernel_scalar(const float* __restrict__ x, float* __restrict__ out,
                     const float* __restrict__ tab, int n,
                     float lo, float hi, float inv_h, int ntab)
{
    int i4 = blockIdx.x * blockDim.x + threadIdx.x;
    int base = i4 * 4;
    for (int k = 0; k < 4; ++k) {
        int idx_e = base + k;
        if (idx_e < n) {
            float xx = fminf(fmaxf(x[idx_e], lo), hi);
            float tt = (xx - lo) * inv_h;
            int idx  = (int)tt;
            idx = idx < (ntab - 1) ? idx : (ntab - 1);
            float fr = tt - (float)idx;
            out[idx_e] = fmaf(fr, tab[idx + 1] - tab[idx], tab[idx]);
        }
    }
}

// Correct-but-slow fallback if workspace can't hold any table.
__global__ void __launch_bounds__(256, 1)
direct_kernel(const float* __restrict__ x, float* __restrict__ out,
              int n, EVAL_PARAMS)
{
    const float* bo1 = gof1;
    int i = blockIdx.x * blockDim.x + threadIdx.x;
    if (i < n)
        out[i] = eval_net(x[i], EVAL_ARGS);
}

extern "C" void kernel_launch(void* const* d_in, const int* in_sizes, int n_in,
                              void* d_out, int out_size, void* d_ws, size_t ws_size,
                              hipStream_t stream) {
    const float* x    = (const float*)d_in[0];
    const float* W1   = (const float*)d_in[1];
    const float* b1   = (const float*)d_in[2];
    const float* g1   = (const float*)d_in[3];
    const float* be1  = (const float*)d_in[4];
    const float* Wih0 = (const float*)d_in[5];
    // d_in[6] = Whh0 (dead: hx==0)
    const float* gi0  = (const float*)d_in[7];
    const float* bi0  = (const float*)d_in[8];
    // d_in[9] = gh0 (dead)
    const float* bh0  = (const float*)d_in[10];
    const float* go0  = (const float*)d_in[11];
    const float* bo0  = (const float*)d_in[12];
    const float* Wih1 = (const float*)d_in[13];
    // d_in[14] = Whh1 (dead)
    const float* gi1  = (const float*)d_in[15];
    const float* bi1  = (const float*)d_in[16];
    // d_in[17] = gh1 (dead)
    const float* bh1  = (const float*)d_in[18];
    const float* go1  = (const float*)d_in[19];
    const float* bo1  = (const float*)d_in[20];
    const float* Wout = (const float*)d_in[21];
    const float* bout = (const float*)d_in[22];

    float* out = (float*)d_out;
    int n = in_sizes[0];

    const int   NTAB = 65536;
    const float LO   = -8.0f, HIv = 8.0f;
    const float hstep = (HIv - LO) / (float)NTAB;

    const size_t pair_bytes = (size_t)NTAB * sizeof(float2);        // 512 KB
    const size_t tmp_bytes  = (size_t)(NTAB + 1) * sizeof(float);   // 256 KB

    if (ws_size >= pair_bytes) {
        float2* tab2 = (float2*)d_ws;
        int bblocks = (NTAB + 1 + 255) / 256;
        build_tab2_kernel<<<bblocks, 256, 0, stream>>>(tab2, NTAB, LO, hstep, EVAL_ARGS);
        int lblocks = ((n + 3) / 4 + 255) / 256;
        lookup_kernel<<<lblocks, 256, 0, stream>>>(x, out, tab2, n, LO, HIv,
                                                   1.0f / hstep, NTAB);
    } else if (ws_size >= tmp_bytes) {
        float* tab = (float*)d_ws;
        int bblocks = (NTAB + 1 + 255) / 256;
        build_tab_kernel<<<bblocks, 256, 0, stream>>>(tab, NTAB, LO, hstep, EVAL_ARGS);
        int lblocks = ((n + 3) / 4 + 255) / 256;
        lookup_kernel_scalar<<<lblocks, 256, 0, stream>>>(x, out, tab, n, LO, HIv,
                                                          1.0f / hstep, NTAB);
    } else {
        int blocks = (n + 255) / 256;
        direct_kernel<<<blocks, 256, 0, stream>>>(x, out, n, EVAL_ARGS);
    }
}

// Round 5
// 163.213 us; speedup vs baseline: 1.7928x; 1.4858x over previous
//
#include <hip/hip_runtime.h>
#include <math.h>

#define H   20
#define H4  80
#define EPSF 1e-5f

// LDS weight-block layout (floats)
#define OFF_W1    0
#define OFF_B1    20
#define OFF_G1    40
#define OFF_BE1   60
#define OFF_WIH0  80
#define OFF_GI0   1680
#define OFF_BI0   1760
#define OFF_BH0   1840
#define OFF_GO0   1920
#define OFF_BO0   1940
#define OFF_WIH1  1960
#define OFF_GI1   3560
#define OFF_BI1   3640
#define OFF_BH1   3720
#define OFF_GO1   3800
#define OFF_BO1   3820
#define OFF_WOUT  3840
#define OFF_BOUT  3860
#define NW        3861

__device__ __forceinline__ float sigm(float v) { return 1.0f / (1.0f + expf(-v)); }

// One LN-LSTM cell, zero initial state, weights in LDS.
//   gates = LN(in @ Wih^T, gi, bi) + bh      (LN(0)=bh exactly; Whh/gh dead)
//   c     = sigmoid(i) * tanh(g)             (f-gate value dead: f*cx = 0)
//   out   = sigmoid(o) * tanh(LN(c, go, bo))
// f-rows (20..39) only feed the LN moments -> accumulate into Sa/Sq, never
// stored. All local arrays fully-unroll-indexed (rule #20: runtime index =>
// scratch; rounds 1-4 burned 150-185us on exactly that).
__device__ __forceinline__ void lstm_layer_lds(
    const float in[H], float out[H],
    const float* Wih, const float* gi, const float* bi, const float* bh,
    const float* go,  const float* bo)
{
    float a60[60];           // i rows -> [0..19], o rows -> [20..39], g rows -> [40..59]
    float Sa = 0.f, Sq = 0.f;
    #pragma unroll
    for (int j = 0; j < H4; ++j) {
        float acc = 0.f;
        #pragma unroll
        for (int h = 0; h < H; ++h)
            acc = fmaf(Wih[j * H + h], in[h], acc);
        Sa += acc;
        Sq = fmaf(acc, acc, Sq);
        if (j < 20)       a60[j]      = acc;   // i
        else if (j >= 40) a60[j - 20] = acc;   // o (20..39), g (40..59)
    }
    float mu  = Sa * (1.0f / H4);
    float var = fmaxf((Sq - Sa * mu) * (1.0f / (H4 - 1)), 0.f);  // ddof=1
    float inv = 1.0f / (sqrtf(var) + EPSF);

    float c[H];
    float Sc = 0.f;
    #pragma unroll
    for (int h = 0; h < H; ++h) {
        float gv_i = fmaf((a60[h]      - mu) * inv, gi[h],      bi[h])      + bh[h];
        float gv_g = fmaf((a60[40 + h] - mu) * inv, gi[60 + h], bi[60 + h]) + bh[60 + h];
        c[h] = sigm(gv_i) * tanhf(gv_g);
        Sc += c[h];
    }
    float mu2  = Sc * (1.0f / H);
    float var2 = 0.f;
    #pragma unroll
    for (int h = 0; h < H; ++h) { float d = c[h] - mu2; var2 = fmaf(d, d, var2); }
    float inv2 = 1.0f / (sqrtf(var2 * (1.0f / (H - 1))) + EPSF);

    #pragma unroll
    for (int h = 0; h < H; ++h) {
        float gv_o = fmaf((a60[20 + h] - mu) * inv, gi[40 + h], bi[40 + h]) + bh[40 + h];
        out[h] = sigm(gv_o) * tanhf((c[h] - mu2) * inv2 * go[h] + bo[h]);
    }
}

// Full scalar->scalar net, weights staged in LDS at w.
__device__ __forceinline__ float eval_net_lds(float x, const float* w)
{
    float cur[H];
    {   // stage 1: LN(x*W1 + b1) -> tanh
        float t[H];
        float mu = 0.f;
        #pragma unroll
        for (int h = 0; h < H; ++h) {
            t[h] = fmaf(x, w[OFF_W1 + h], w[OFF_B1 + h]);
            mu += t[h];
        }
        mu *= (1.0f / H);
        float var = 0.f;
        #pragma unroll
        for (int h = 0; h < H; ++h) { float d = t[h] - mu; var = fmaf(d, d, var); }
        float inv = 1.0f / (sqrtf(var * (1.0f / (H - 1))) + EPSF);
        #pragma unroll
        for (int h = 0; h < H; ++h)
            cur[h] = tanhf((t[h] - mu) * inv * w[OFF_G1 + h] + w[OFF_BE1 + h]);
    }
    float nxt[H];
    lstm_layer_lds(cur, nxt, w + OFF_WIH0, w + OFF_GI0, w + OFF_BI0,
                   w + OFF_BH0, w + OFF_GO0, w + OFF_BO0);
    lstm_layer_lds(nxt, cur, w + OFF_WIH1, w + OFF_GI1, w + OFF_BI1,
                   w + OFF_BH1, w + OFF_GO1, w + OFF_BO1);

    float r = w[OFF_BOUT];
    #pragma unroll
    for (int h = 0; h < H; ++h) r = fmaf(cur[h], w[OFF_WOUT + h], r);
    return r;
}

#define EVAL_PARAMS \
    const float* __restrict__ W1,   const float* __restrict__ b1,   \
    const float* __restrict__ g1,   const float* __restrict__ be1,  \
    const float* __restrict__ Wih0, const float* __restrict__ gi0,  \
    const float* __restrict__ bi0,  const float* __restrict__ bh0,  \
    const float* __restrict__ go0,  const float* __restrict__ bo0,  \
    const float* __restrict__ Wih1, const float* __restrict__ gi1,  \
    const float* __restrict__ bi1,  const float* __restrict__ bh1,  \
    const float* __restrict__ go1,  const float* __restrict__ bo1,  \
    const float* __restrict__ Wout, const float* __restrict__ bout
#define EVAL_ARGS W1, b1, g1, be1, Wih0, gi0, bi0, bh0, go0, bo0, \
                  Wih1, gi1, bi1, bh1, go1, bo1, Wout, bout

// Cooperative copy of all weights into LDS. Each helper call is inlined with
// a constant length; no runtime-indexed pointer arrays.
__device__ __forceinline__ void stage_weights(float* w, int tid, EVAL_PARAMS)
{
    #define CPY(OFFC, SRC, LEN)                               \
        for (int i = tid; i < (LEN); i += 256) w[(OFFC) + i] = (SRC)[i];
    CPY(OFF_W1,   W1,   20)   CPY(OFF_B1,   b1,   20)
    CPY(OFF_G1,   g1,   20)   CPY(OFF_BE1,  be1,  20)
    CPY(OFF_WIH0, Wih0, 1600) CPY(OFF_GI0,  gi0,  80)
    CPY(OFF_BI0,  bi0,  80)   CPY(OFF_BH0,  bh0,  80)
    CPY(OFF_GO0,  go0,  20)   CPY(OFF_BO0,  bo0,  20)
    CPY(OFF_WIH1, Wih1, 1600) CPY(OFF_GI1,  gi1,  80)
    CPY(OFF_BI1,  bi1,  80)   CPY(OFF_BH1,  bh1,  80)
    CPY(OFF_GO1,  go1,  20)   CPY(OFF_BO1,  bo1,  20)
    CPY(OFF_WOUT, Wout, 20)   CPY(OFF_BOUT, bout, 1)
    #undef CPY
    __syncthreads();
}

// Build the PAIRED table: thread i computes F_i and writes
//   tab2[i].x = F_i (i<ntab);  tab2[i-1].y = F_i (i>0).  No race.
__global__ void __launch_bounds__(256, 1)
build_tab2_kernel(float2* __restrict__ tab2, int ntab,
                  float lo, float hstep, EVAL_PARAMS)
{
    __shared__ float w[NW];
    stage_weights(w, threadIdx.x, EVAL_ARGS);
    int i = blockIdx.x * blockDim.x + threadIdx.x;
    if (i <= ntab) {
        float v = eval_net_lds(lo + hstep * (float)i, w);
        if (i < ntab) tab2[i].x     = v;
        if (i > 0)    tab2[i - 1].y = v;
    }
}

// Scalar-table builder (fallback path).
__global__ void __launch_bounds__(256, 1)
build_tab_kernel(float* __restrict__ tab, int ntab,
                 float lo, float hstep, EVAL_PARAMS)
{
    __shared__ float w[NW];
    stage_weights(w, threadIdx.x, EVAL_ARGS);
    int i = blockIdx.x * blockDim.x + threadIdx.x;
    if (i <= ntab)
        tab[i] = eval_net_lds(lo + hstep * (float)i, w);
}

// out[i] = lerp over tab2 at clamp(x[i])
__global__ void __launch_bounds__(256)
lookup_kernel(const float* __restrict__ x, float* __restrict__ out,
              const float2* __restrict__ tab2, int n,
              float lo, float hi, float inv_h, int ntab)
{
    int i4 = blockIdx.x * blockDim.x + threadIdx.x;
    int base = i4 * 4;
    if (base + 3 < n) {
        float4 v = *reinterpret_cast<const float4*>(x + base);
        float r[4];
        float xs[4] = {v.x, v.y, v.z, v.w};
        #pragma unroll
        for (int k = 0; k < 4; ++k) {
            float xx = fminf(fmaxf(xs[k], lo), hi);
            float tt = (xx - lo) * inv_h;
            int idx  = (int)tt;
            idx = idx < (ntab - 1) ? idx : (ntab - 1);
            float fr = tt - (float)idx;
            float2 p = tab2[idx];
            r[k] = fmaf(fr, p.y - p.x, p.x);
        }
        float4 o = make_float4(r[0], r[1], r[2], r[3]);
        *reinterpret_cast<float4*>(out + base) = o;
    } else {
        for (int k = 0; k < 4; ++k) {
            int idx_e = base + k;
            if (idx_e < n) {
                float xx = fminf(fmaxf(x[idx_e], lo), hi);
                float tt = (xx - lo) * inv_h;
                int idx  = (int)tt;
                idx = idx < (ntab - 1) ? idx : (ntab - 1);
                float fr = tt - (float)idx;
                float2 p = tab2[idx];
                out[idx_e] = fmaf(fr, p.y - p.x, p.x);
            }
        }
    }
}

// Scalar-table lookup (fallback when ws can't hold the paired table).
__global__ void __launch_bounds__(256)
lookup_kernel_scalar(const float* __restrict__ x, float* __restrict__ out,
                     const float* __restrict__ tab, int n,
                     float lo, float hi, float inv_h, int ntab)
{
    int i4 = blockIdx.x * blockDim.x + threadIdx.x;
    int base = i4 * 4;
    for (int k = 0; k < 4; ++k) {
        int idx_e = base + k;
        if (idx_e < n) {
            float xx = fminf(fmaxf(x[idx_e], lo), hi);
            float tt = (xx - lo) * inv_h;
            int idx  = (int)tt;
            idx = idx < (ntab - 1) ? idx : (ntab - 1);
            float fr = tt - (float)idx;
            out[idx_e] = fmaf(fr, tab[idx + 1] - tab[idx], tab[idx]);
        }
    }
}

// Correct-but-slow fallback if workspace can't hold any table.
__global__ void __launch_bounds__(256, 1)
direct_kernel(const float* __restrict__ x, float* __restrict__ out,
              int n, EVAL_PARAMS)
{
    __shared__ float w[NW];
    stage_weights(w, threadIdx.x, EVAL_ARGS);
    int i = blockIdx.x * blockDim.x + threadIdx.x;
    if (i < n)
        out[i] = eval_net_lds(x[i], w);
}

extern "C" void kernel_launch(void* const* d_in, const int* in_sizes, int n_in,
                              void* d_out, int out_size, void* d_ws, size_t ws_size,
                              hipStream_t stream) {
    const float* x    = (const float*)d_in[0];
    const float* W1   = (const float*)d_in[1];
    const float* b1   = (const float*)d_in[2];
    const float* g1   = (const float*)d_in[3];
    const float* be1  = (const float*)d_in[4];
    const float* Wih0 = (const float*)d_in[5];
    // d_in[6] = Whh0 (dead: hx==0)
    const float* gi0  = (const float*)d_in[7];
    const float* bi0  = (const float*)d_in[8];
    // d_in[9] = gh0 (dead)
    const float* bh0  = (const float*)d_in[10];
    const float* go0  = (const float*)d_in[11];
    const float* bo0  = (const float*)d_in[12];
    const float* Wih1 = (const float*)d_in[13];
    // d_in[14] = Whh1 (dead)
    const float* gi1  = (const float*)d_in[15];
    const float* bi1  = (const float*)d_in[16];
    // d_in[17] = gh1 (dead)
    const float* bh1  = (const float*)d_in[18];
    const float* go1  = (const float*)d_in[19];
    const float* bo1  = (const float*)d_in[20];
    const float* Wout = (const float*)d_in[21];
    const float* bout = (const float*)d_in[22];

    float* out = (float*)d_out;
    int n = in_sizes[0];

    const int   NTAB = 65536;
    const float LO   = -8.0f, HIv = 8.0f;
    const float hstep = (HIv - LO) / (float)NTAB;

    const size_t pair_bytes = (size_t)NTAB * sizeof(float2);        // 512 KB
    const size_t tmp_bytes  = (size_t)(NTAB + 1) * sizeof(float);   // 256 KB

    if (ws_size >= pair_bytes) {
        float2* tab2 = (float2*)d_ws;
        int bblocks = (NTAB + 1 + 255) / 256;
        build_tab2_kernel<<<bblocks, 256, 0, stream>>>(tab2, NTAB, LO, hstep, EVAL_ARGS);
        int lblocks = ((n + 3) / 4 + 255) / 256;
        lookup_kernel<<<lblocks, 256, 0, stream>>>(x, out, tab2, n, LO, HIv,
                                                   1.0f / hstep, NTAB);
    } else if (ws_size >= tmp_bytes) {
        float* tab = (float*)d_ws;
        int bblocks = (NTAB + 1 + 255) / 256;
        build_tab_kernel<<<bblocks, 256, 0, stream>>>(tab, NTAB, LO, hstep, EVAL_ARGS);
        int lblocks = ((n + 3) / 4 + 255) / 256;
        lookup_kernel_scalar<<<lblocks, 256, 0, stream>>>(x, out, tab, n, LO, HIv,
                                                          1.0f / hstep, NTAB);
    } else {
        int blocks = (n + 255) / 256;
        direct_kernel<<<blocks, 256, 0, stream>>>(x, out, n, EVAL_ARGS);
    }
}

// Round 6
// 148.427 us; speedup vs baseline: 1.9715x; 1.0996x over previous
//
#include <hip/hip_runtime.h>
#include <math.h>

#define H   20
#define H4  80
#define EPSF 1e-5f

typedef float f32x4 __attribute__((ext_vector_type(4)));

// LDS weight-block layout (floats)
#define OFF_W1    0
#define OFF_B1    20
#define OFF_G1    40
#define OFF_BE1   60
#define OFF_WIH0  80
#define OFF_GI0   1680
#define OFF_BI0   1760
#define OFF_BH0   1840
#define OFF_GO0   1920
#define OFF_BO0   1940
#define OFF_WIH1  1960
#define OFF_GI1   3560
#define OFF_BI1   3640
#define OFF_BH1   3720
#define OFF_GO1   3800
#define OFF_BO1   3820
#define OFF_WOUT  3840
#define OFF_BOUT  3860
#define NW        3861

// Fast transcendentals: v_exp_f32-based. Round-5 counters showed the builder
// chain is latency-bound (VALUBusy 30%, HBM 0.3%) on libm tanhf/expf chains.
// Abs error ~1e-6, far under the ~3.4e-3 threshold (observed comparison
// quantization floor is 2^-10 regardless of our math).
__device__ __forceinline__ float fast_sigm(float v) {
    return 1.0f / (1.0f + __expf(-v));
}
__device__ __forceinline__ float fast_tanh(float v) {
    return 2.0f / (1.0f + __expf(-2.0f * v)) - 1.0f;
}

// One LN-LSTM cell, zero initial state, weights in LDS.
//   gates = LN(in @ Wih^T, gi, bi) + bh      (LN(0)=bh exactly; Whh/gh dead)
//   c     = sigmoid(i) * tanh(g)             (f-gate value dead: f*cx = 0)
//   out   = sigmoid(o) * tanh(LN(c, go, bo))
// f-rows (20..39) only feed the LN moments -> folded into Sa/Sq, never stored.
// All local arrays fully-unroll-indexed (rule #20: runtime index => scratch).
__device__ __forceinline__ void lstm_layer_lds(
    const float in[H], float out[H],
    const float* Wih, const float* gi, const float* bi, const float* bh,
    const float* go,  const float* bo)
{
    float a60[60];           // i rows -> [0..19], o rows -> [20..39], g rows -> [40..59]
    float Sa = 0.f, Sq = 0.f;
    #pragma unroll
    for (int j = 0; j < H4; ++j) {
        float acc = 0.f;
        #pragma unroll
        for (int h = 0; h < H; ++h)
            acc = fmaf(Wih[j * H + h], in[h], acc);
        Sa += acc;
        Sq = fmaf(acc, acc, Sq);
        if (j < 20)       a60[j]      = acc;   // i
        else if (j >= 40) a60[j - 20] = acc;   // o (20..39), g (40..59)
    }
    float mu  = Sa * (1.0f / H4);
    float var = fmaxf((Sq - Sa * mu) * (1.0f / (H4 - 1)), 0.f);  // ddof=1
    float inv = 1.0f / (sqrtf(var) + EPSF);

    float c[H];
    float Sc = 0.f;
    #pragma unroll
    for (int h = 0; h < H; ++h) {
        float gv_i = fmaf((a60[h]      - mu) * inv, gi[h],      bi[h])      + bh[h];
        float gv_g = fmaf((a60[40 + h] - mu) * inv, gi[60 + h], bi[60 + h]) + bh[60 + h];
        c[h] = fast_sigm(gv_i) * fast_tanh(gv_g);
        Sc += c[h];
    }
    float mu2  = Sc * (1.0f / H);
    float var2 = 0.f;
    #pragma unroll
    for (int h = 0; h < H; ++h) { float d = c[h] - mu2; var2 = fmaf(d, d, var2); }
    float inv2 = 1.0f / (sqrtf(var2 * (1.0f / (H - 1))) + EPSF);

    #pragma unroll
    for (int h = 0; h < H; ++h) {
        float gv_o = fmaf((a60[20 + h] - mu) * inv, gi[40 + h], bi[40 + h]) + bh[40 + h];
        out[h] = fast_sigm(gv_o) * fast_tanh((c[h] - mu2) * inv2 * go[h] + bo[h]);
    }
}

// Full scalar->scalar net, weights staged in LDS at w.
__device__ __forceinline__ float eval_net_lds(float x, const float* w)
{
    float cur[H];
    {   // stage 1: LN(x*W1 + b1) -> tanh
        float t[H];
        float mu = 0.f;
        #pragma unroll
        for (int h = 0; h < H; ++h) {
            t[h] = fmaf(x, w[OFF_W1 + h], w[OFF_B1 + h]);
            mu += t[h];
        }
        mu *= (1.0f / H);
        float var = 0.f;
        #pragma unroll
        for (int h = 0; h < H; ++h) { float d = t[h] - mu; var = fmaf(d, d, var); }
        float inv = 1.0f / (sqrtf(var * (1.0f / (H - 1))) + EPSF);
        #pragma unroll
        for (int h = 0; h < H; ++h)
            cur[h] = fast_tanh((t[h] - mu) * inv * w[OFF_G1 + h] + w[OFF_BE1 + h]);
    }
    float nxt[H];
    lstm_layer_lds(cur, nxt, w + OFF_WIH0, w + OFF_GI0, w + OFF_BI0,
                   w + OFF_BH0, w + OFF_GO0, w + OFF_BO0);
    lstm_layer_lds(nxt, cur, w + OFF_WIH1, w + OFF_GI1, w + OFF_BI1,
                   w + OFF_BH1, w + OFF_GO1, w + OFF_BO1);

    float r = w[OFF_BOUT];
    #pragma unroll
    for (int h = 0; h < H; ++h) r = fmaf(cur[h], w[OFF_WOUT + h], r);
    return r;
}

#define EVAL_PARAMS \
    const float* __restrict__ W1,   const float* __restrict__ b1,   \
    const float* __restrict__ g1,   const float* __restrict__ be1,  \
    const float* __restrict__ Wih0, const float* __restrict__ gi0,  \
    const float* __restrict__ bi0,  const float* __restrict__ bh0,  \
    const float* __restrict__ go0,  const float* __restrict__ bo0,  \
    const float* __restrict__ Wih1, const float* __restrict__ gi1,  \
    const float* __restrict__ bi1,  const float* __restrict__ bh1,  \
    const float* __restrict__ go1,  const float* __restrict__ bo1,  \
    const float* __restrict__ Wout, const float* __restrict__ bout
#define EVAL_ARGS W1, b1, g1, be1, Wih0, gi0, bi0, bh0, go0, bo0, \
                  Wih1, gi1, bi1, bh1, go1, bo1, Wout, bout

// Cooperative copy of all weights into LDS (constant-length inlined copies).
__device__ __forceinline__ void stage_weights(float* w, int tid, EVAL_PARAMS)
{
    #define CPY(OFFC, SRC, LEN)                               \
        for (int i = tid; i < (LEN); i += 256) w[(OFFC) + i] = (SRC)[i];
    CPY(OFF_W1,   W1,   20)   CPY(OFF_B1,   b1,   20)
    CPY(OFF_G1,   g1,   20)   CPY(OFF_BE1,  be1,  20)
    CPY(OFF_WIH0, Wih0, 1600) CPY(OFF_GI0,  gi0,  80)
    CPY(OFF_BI0,  bi0,  80)   CPY(OFF_BH0,  bh0,  80)
    CPY(OFF_GO0,  go0,  20)   CPY(OFF_BO0,  bo0,  20)
    CPY(OFF_WIH1, Wih1, 1600) CPY(OFF_GI1,  gi1,  80)
    CPY(OFF_BI1,  bi1,  80)   CPY(OFF_BH1,  bh1,  80)
    CPY(OFF_GO1,  go1,  20)   CPY(OFF_BO1,  bo1,  20)
    CPY(OFF_WOUT, Wout, 20)   CPY(OFF_BOUT, bout, 1)
    #undef CPY
    __syncthreads();
}

// ---- Cubic (Catmull-Rom) table, NTAB=1024 intervals over [-8,8] ----
// samples[j] = F(lo + (j-1)*h), j = 0..NTAB+2  (ghost points at both ends)
// coef[i] (float4) = CR cubic on interval i from samples[i..i+3].
// 16 KB coef table -> L1-resident during lookup.

__global__ void __launch_bounds__(256, 1)
build_samples_kernel(float* __restrict__ samples, int nsamp,
                     float lo, float hstep, EVAL_PARAMS)
{
    __shared__ float w[NW];
    stage_weights(w, threadIdx.x, EVAL_ARGS);
    int j = blockIdx.x * blockDim.x + threadIdx.x;
    if (j < nsamp)
        samples[j] = eval_net_lds(lo + hstep * (float)(j - 1), w);
}

__global__ void pack_coef_kernel(const float* __restrict__ samples,
                                 f32x4* __restrict__ coef, int ntab)
{
    int i = blockIdx.x * blockDim.x + threadIdx.x;
    if (i < ntab) {
        float p0 = samples[i];
        float p1 = samples[i + 1];
        float p2 = samples[i + 2];
        float p3 = samples[i + 3];
        f32x4 c;
        c.x = p1;
        c.y = 0.5f * (p2 - p0);
        c.z = p0 - 2.5f * p1 + 2.0f * p2 - 0.5f * p3;
        c.w = 1.5f * (p1 - p2) + 0.5f * (p3 - p0);
        coef[i] = c;
    }
}

// out[i] = cubic(coef, clamp(x[i])). Non-temporal on the x/out streams so the
// 16 KB coef table stays L1-resident.
__global__ void __launch_bounds__(256)
lookup_cubic_kernel(const float* __restrict__ x, float* __restrict__ out,
                    const f32x4* __restrict__ coef, int n,
                    float lo, float hi, float inv_h, int ntab)
{
    int n4 = n >> 2;
    int stride = gridDim.x * blockDim.x;
    const f32x4* x4 = reinterpret_cast<const f32x4*>(x);
    f32x4* o4 = reinterpret_cast<f32x4*>(out);
    for (int i = blockIdx.x * blockDim.x + threadIdx.x; i < n4; i += stride) {
        f32x4 v = __builtin_nontemporal_load(x4 + i);
        f32x4 r;
        #pragma unroll
        for (int k = 0; k < 4; ++k) {
            float xx = fminf(fmaxf(v[k], lo), hi);
            float tt = (xx - lo) * inv_h;
            int idx  = (int)tt;
            idx = idx < (ntab - 1) ? idx : (ntab - 1);
            float fr = tt - (float)idx;
            f32x4 cf = coef[idx];
            r[k] = fmaf(fmaf(fmaf(cf.w, fr, cf.z), fr, cf.y), fr, cf.x);
        }
        __builtin_nontemporal_store(r, o4 + i);
    }
    // tail (n % 4 elements)
    int rem = n & 3;
    if (blockIdx.x == 0 && (int)threadIdx.x < rem) {
        int e = n4 * 4 + threadIdx.x;
        float xx = fminf(fmaxf(x[e], lo), hi);
        float tt = (xx - lo) * inv_h;
        int idx  = (int)tt;
        idx = idx < (ntab - 1) ? idx : (ntab - 1);
        float fr = tt - (float)idx;
        f32x4 cf = coef[idx];
        out[e] = fmaf(fmaf(fmaf(cf.w, fr, cf.z), fr, cf.y), fr, cf.x);
    }
}

// Correct-but-slow fallback if workspace can't hold the tables.
__global__ void __launch_bounds__(256, 1)
direct_kernel(const float* __restrict__ x, float* __restrict__ out,
              int n, EVAL_PARAMS)
{
    __shared__ float w[NW];
    stage_weights(w, threadIdx.x, EVAL_ARGS);
    int i = blockIdx.x * blockDim.x + threadIdx.x;
    if (i < n)
        out[i] = eval_net_lds(x[i], w);
}

extern "C" void kernel_launch(void* const* d_in, const int* in_sizes, int n_in,
                              void* d_out, int out_size, void* d_ws, size_t ws_size,
                              hipStream_t stream) {
    const float* x    = (const float*)d_in[0];
    const float* W1   = (const float*)d_in[1];
    const float* b1   = (const float*)d_in[2];
    const float* g1   = (const float*)d_in[3];
    const float* be1  = (const float*)d_in[4];
    const float* Wih0 = (const float*)d_in[5];
    // d_in[6] = Whh0 (dead: hx==0)
    const float* gi0  = (const float*)d_in[7];
    const float* bi0  = (const float*)d_in[8];
    // d_in[9] = gh0 (dead)
    const float* bh0  = (const float*)d_in[10];
    const float* go0  = (const float*)d_in[11];
    const float* bo0  = (const float*)d_in[12];
    const float* Wih1 = (const float*)d_in[13];
    // d_in[14] = Whh1 (dead)
    const float* gi1  = (const float*)d_in[15];
    const float* bi1  = (const float*)d_in[16];
    // d_in[17] = gh1 (dead)
    const float* bh1  = (const float*)d_in[18];
    const float* go1  = (const float*)d_in[19];
    const float* bo1  = (const float*)d_in[20];
    const float* Wout = (const float*)d_in[21];
    const float* bout = (const float*)d_in[22];

    float* out = (float*)d_out;
    int n = in_sizes[0];

    const int   NTAB  = 1024;          // intervals
    const int   NSAMP = NTAB + 3;      // with ghost points
    const float LO    = -8.0f, HIv = 8.0f;
    const float hstep = (HIv - LO) / (float)NTAB;

    const size_t coef_bytes = (size_t)NTAB * sizeof(f32x4);       // 16 KB
    const size_t samp_bytes = (size_t)NSAMP * sizeof(float);      // ~4.1 KB

    if (ws_size >= coef_bytes + samp_bytes) {
        f32x4* coef    = (f32x4*)d_ws;                 // 16B-aligned at ws base
        float* samples = (float*)((char*)d_ws + coef_bytes);

        int bblocks = (NSAMP + 255) / 256;             // 5 blocks
        build_samples_kernel<<<bblocks, 256, 0, stream>>>(samples, NSAMP, LO,
                                                          hstep, EVAL_ARGS);
        int pblocks = (NTAB + 255) / 256;              // 4 blocks
        pack_coef_kernel<<<pblocks, 256, 0, stream>>>(samples, coef, NTAB);

        int want = (n / 4 + 255) / 256;
        int lblocks = want < 2048 ? want : 2048;       // grid-stride cap (G11)
        lookup_cubic_kernel<<<lblocks, 256, 0, stream>>>(x, out, coef, n, LO,
                                                         HIv, 1.0f / hstep, NTAB);
    } else {
        int blocks = (n + 255) / 256;
        direct_kernel<<<blocks, 256, 0, stream>>>(x, out, n, EVAL_ARGS);
    }
}

// Round 7
// 133.579 us; speedup vs baseline: 2.1906x; 1.1111x over previous
//
#include <hip/hip_runtime.h>
#include <math.h>

#define H   20
#define H4  80
#define EPSF 1e-5f

typedef float f32x4 __attribute__((ext_vector_type(4)));

// LDS weight-block layout (floats)
#define OFF_W1    0
#define OFF_B1    20
#define OFF_G1    40
#define OFF_BE1   60
#define OFF_WIH0  80
#define OFF_GI0   1680
#define OFF_BI0   1760
#define OFF_BH0   1840
#define OFF_GO0   1920
#define OFF_BO0   1940
#define OFF_WIH1  1960
#define OFF_GI1   3560
#define OFF_BI1   3640
#define OFF_BH1   3720
#define OFF_GO1   3800
#define OFF_BO1   3820
#define OFF_WOUT  3840
#define OFF_BOUT  3860
#define NW        3861

__device__ __forceinline__ float fast_sigm(float v) {
    return 1.0f / (1.0f + __expf(-v));
}
__device__ __forceinline__ float fast_tanh(float v) {
    return 2.0f / (1.0f + __expf(-2.0f * v)) - 1.0f;
}

// Sum across an aligned 4-lane quad (lanes q, q^1, q^2, q^3).
__device__ __forceinline__ float qsum(float v) {
    v += __shfl_xor(v, 1);
    v += __shfl_xor(v, 2);
    return v;
}

#define EVAL_PARAMS \
    const float* __restrict__ W1,   const float* __restrict__ b1,   \
    const float* __restrict__ g1,   const float* __restrict__ be1,  \
    const float* __restrict__ Wih0, const float* __restrict__ gi0,  \
    const float* __restrict__ bi0,  const float* __restrict__ bh0,  \
    const float* __restrict__ go0,  const float* __restrict__ bo0,  \
    const float* __restrict__ Wih1, const float* __restrict__ gi1,  \
    const float* __restrict__ bi1,  const float* __restrict__ bh1,  \
    const float* __restrict__ go1,  const float* __restrict__ bo1,  \
    const float* __restrict__ Wout, const float* __restrict__ bout
#define EVAL_ARGS W1, b1, g1, be1, Wih0, gi0, bi0, bh0, go0, bo0, \
                  Wih1, gi1, bi1, bh1, go1, bo1, Wout, bout

// Cooperative copy of all weights into LDS (runtime stride is fine: LDS/global
// addressing, not register-array indexing).
__device__ __forceinline__ void stage_weights(float* w, int tid, int nthr,
                                              EVAL_PARAMS)
{
    #define CPY(OFFC, SRC, LEN)                                   \
        for (int i = tid; i < (LEN); i += nthr) w[(OFFC) + i] = (SRC)[i];
    CPY(OFF_W1,   W1,   20)   CPY(OFF_B1,   b1,   20)
    CPY(OFF_G1,   g1,   20)   CPY(OFF_BE1,  be1,  20)
    CPY(OFF_WIH0, Wih0, 1600) CPY(OFF_GI0,  gi0,  80)
    CPY(OFF_BI0,  bi0,  80)   CPY(OFF_BH0,  bh0,  80)
    CPY(OFF_GO0,  go0,  20)   CPY(OFF_BO0,  bo0,  20)
    CPY(OFF_WIH1, Wih1, 1600) CPY(OFF_GI1,  gi1,  80)
    CPY(OFF_BI1,  bi1,  80)   CPY(OFF_BH1,  bh1,  80)
    CPY(OFF_GO1,  go1,  20)   CPY(OFF_BO1,  bo1,  20)
    CPY(OFF_WOUT, Wout, 20)   CPY(OFF_BOUT, bout, 1)
    #undef CPY
    __syncthreads();
}

// ---- Quad-parallel evaluation: 4 lanes cooperate on ONE sample ----
// Key structure: gate rows i=h, o=40+h, g=60+h are all == h (mod 4), so
// lane q owns h in {q, q+4, q+8, q+12, q+16} for ALL per-h gate math with no
// cross-lane gathers. Only LN moments + final dot need qsum (2x shfl_xor).
// f-rows (20..39) are computed for the LN moments only (f*cx = 0).
// All register arrays statically indexed (rule #20).
__device__ float eval_quad(float x, const float* w, int q, int lane)
{
    int qb = lane & ~3;     // quad base lane (for shfl broadcast)

    // stage 1: LN(x*W1 + b1) -> tanh ; lane q owns h = q+4m
    float t5[5], cur5[5];
    #pragma unroll
    for (int m = 0; m < 5; ++m)
        t5[m] = fmaf(x, w[OFF_W1 + q + 4 * m], w[OFF_B1 + q + 4 * m]);
    float S = 0.f;
    #pragma unroll
    for (int m = 0; m < 5; ++m) S += t5[m];
    S = qsum(S);
    float mu = S * (1.0f / H);
    float V = 0.f;
    #pragma unroll
    for (int m = 0; m < 5; ++m) { float d = t5[m] - mu; V = fmaf(d, d, V); }
    V = qsum(V);
    float inv = 1.0f / (sqrtf(V * (1.0f / (H - 1))) + EPSF);
    #pragma unroll
    for (int m = 0; m < 5; ++m)
        cur5[m] = fast_tanh((t5[m] - mu) * inv * w[OFF_G1 + q + 4 * m]
                            + w[OFF_BE1 + q + 4 * m]);

    // two LN-LSTM layers
    #pragma unroll
    for (int layer = 0; layer < 2; ++layer) {
        const float* Wih = w + (layer ? OFF_WIH1 : OFF_WIH0);
        const float* gi  = w + (layer ? OFF_GI1  : OFF_GI0);
        const float* bi  = w + (layer ? OFF_BI1  : OFF_BI0);
        const float* bh  = w + (layer ? OFF_BH1  : OFF_BH0);
        const float* go  = w + (layer ? OFF_GO1  : OFF_GO0);
        const float* bo  = w + (layer ? OFF_BO1  : OFF_BO0);

        // broadcast the quad-distributed input vector into all 4 lanes
        float in20[20];
        #pragma unroll
        for (int m = 0; m < 5; ++m) {
            #pragma unroll
            for (int qq = 0; qq < 4; ++qq)
                in20[4 * m + qq] = __shfl(cur5[m], qb + qq, 64);
        }

        // matvec: lane q computes rows r = q+4k, k=0..19 (20 of 80 rows)
        float a20[20];
        #pragma unroll
        for (int k = 0; k < 20; ++k) {
            int r = q + 4 * k;
            float acc = 0.f;
            #pragma unroll
            for (int h = 0; h < H; ++h)
                acc = fmaf(Wih[r * H + h], in20[h], acc);
            a20[k] = acc;
        }
        // LN moments over all 80 rows (two-pass, ddof=1)
        float Sa = 0.f;
        #pragma unroll
        for (int k = 0; k < 20; ++k) Sa += a20[k];
        Sa = qsum(Sa);
        float mug = Sa * (1.0f / H4);
        float Vg = 0.f;
        #pragma unroll
        for (int k = 0; k < 20; ++k) { float d = a20[k] - mug; Vg = fmaf(d, d, Vg); }
        Vg = qsum(Vg);
        float invg = 1.0f / (sqrtf(Vg * (1.0f / (H4 - 1))) + EPSF);

        // c = sigm(i)*tanh(g): i rows k=0..4 (r=h), g rows k=15..19 (r=60+h)
        float c5[5];
        float Sc = 0.f;
        #pragma unroll
        for (int m = 0; m < 5; ++m) {
            int ri = q + 4 * m;          // i row (= h)
            int rg = 60 + q + 4 * m;     // g row
            float gv_i = fmaf((a20[m]      - mug) * invg, gi[ri], bi[ri]) + bh[ri];
            float gv_g = fmaf((a20[15 + m] - mug) * invg, gi[rg], bi[rg]) + bh[rg];
            c5[m] = fast_sigm(gv_i) * fast_tanh(gv_g);
            Sc += c5[m];
        }
        Sc = qsum(Sc);
        float mu2 = Sc * (1.0f / H);
        float V2 = 0.f;
        #pragma unroll
        for (int m = 0; m < 5; ++m) { float d = c5[m] - mu2; V2 = fmaf(d, d, V2); }
        V2 = qsum(V2);
        float inv2 = 1.0f / (sqrtf(V2 * (1.0f / (H - 1))) + EPSF);

        // out = sigm(o)*tanh(LN(c)): o rows k=10..14 (r=40+h)
        #pragma unroll
        for (int m = 0; m < 5; ++m) {
            int h  = q + 4 * m;
            int ro = 40 + h;
            float gv_o = fmaf((a20[10 + m] - mug) * invg, gi[ro], bi[ro]) + bh[ro];
            cur5[m] = fast_sigm(gv_o)
                    * fast_tanh((c5[m] - mu2) * inv2 * go[h] + bo[h]);
        }
    }

    // final dot: out @ Wout + bout
    float rp = 0.f;
    #pragma unroll
    for (int m = 0; m < 5; ++m)
        rp = fmaf(cur5[m], w[OFF_WOUT + q + 4 * m], rp);
    rp = qsum(rp);
    return rp + w[OFF_BOUT];
}

// ---- Fused builder: samples (quad-parallel) + Catmull-Rom coef pack ----
// NTAB=1024 intervals over [-8,8]; 16 blocks x 320 threads (80 quads).
// Block b: quads g=0..66 compute samples j = 64b+g (sample j = F(lo+(j-1)h),
// 3-sample overlap with next block); then threads 0..63 emit coef[64b+t]
// from s_samp[t..t+3]. 16 KB coef table -> L1-resident during lookup.
#define BQ_THREADS 320
__global__ void __launch_bounds__(BQ_THREADS, 1)
build_coef_kernel(f32x4* __restrict__ coef, float lo, float hstep, EVAL_PARAMS)
{
    __shared__ float w[NW];
    __shared__ float s_samp[67];
    stage_weights(w, threadIdx.x, BQ_THREADS, EVAL_ARGS);

    int g    = threadIdx.x >> 2;
    int q    = threadIdx.x & 3;
    int lane = threadIdx.x & 63;
    int s0   = blockIdx.x * 64;
    if (g < 67) {
        int j = s0 + g;                          // 0..1026
        float xv = lo + hstep * (float)(j - 1);  // ghost point at j=0
        float v  = eval_quad(xv, w, q, lane);
        if (q == 0) s_samp[g] = v;
    }
    __syncthreads();

    int t = threadIdx.x;
    if (t < 64) {
        float p0 = s_samp[t];
        float p1 = s_samp[t + 1];
        float p2 = s_samp[t + 2];
        float p3 = s_samp[t + 3];
        f32x4 c;
        c.x = p1;
        c.y = 0.5f * (p2 - p0);
        c.z = p0 - 2.5f * p1 + 2.0f * p2 - 0.5f * p3;
        c.w = 1.5f * (p1 - p2) + 0.5f * (p3 - p0);
        coef[s0 + t] = c;
    }
}

// out[i] = cubic(coef, clamp(x[i])). Non-temporal on the x/out streams so the
// 16 KB coef table stays L1-resident.
__global__ void __launch_bounds__(256)
lookup_cubic_kernel(const float* __restrict__ x, float* __restrict__ out,
                    const f32x4* __restrict__ coef, int n,
                    float lo, float hi, float inv_h, int ntab)
{
    int n4 = n >> 2;
    int stride = gridDim.x * blockDim.x;
    const f32x4* x4 = reinterpret_cast<const f32x4*>(x);
    f32x4* o4 = reinterpret_cast<f32x4*>(out);
    for (int i = blockIdx.x * blockDim.x + threadIdx.x; i < n4; i += stride) {
        f32x4 v = __builtin_nontemporal_load(x4 + i);
        f32x4 r;
        #pragma unroll
        for (int k = 0; k < 4; ++k) {
            float xx = fminf(fmaxf(v[k], lo), hi);
            float tt = (xx - lo) * inv_h;
            int idx  = (int)tt;
            idx = idx < (ntab - 1) ? idx : (ntab - 1);
            float fr = tt - (float)idx;
            f32x4 cf = coef[idx];
            r[k] = fmaf(fmaf(fmaf(cf.w, fr, cf.z), fr, cf.y), fr, cf.x);
        }
        __builtin_nontemporal_store(r, o4 + i);
    }
    int rem = n & 3;
    if (blockIdx.x == 0 && (int)threadIdx.x < rem) {
        int e = n4 * 4 + threadIdx.x;
        float xx = fminf(fmaxf(x[e], lo), hi);
        float tt = (xx - lo) * inv_h;
        int idx  = (int)tt;
        idx = idx < (ntab - 1) ? idx : (ntab - 1);
        float fr = tt - (float)idx;
        f32x4 cf = coef[idx];
        out[e] = fmaf(fmaf(fmaf(cf.w, fr, cf.z), fr, cf.y), fr, cf.x);
    }
}

// ---- Fallback: direct per-element eval (only if ws can't hold 16 KB) ----
__device__ __forceinline__ void lstm_layer_lds(
    const float in[H], float out[H],
    const float* Wih, const float* gi, const float* bi, const float* bh,
    const float* go,  const float* bo)
{
    float a60[60];
    float Sa = 0.f, Sq = 0.f;
    #pragma unroll
    for (int j = 0; j < H4; ++j) {
        float acc = 0.f;
        #pragma unroll
        for (int h = 0; h < H; ++h)
            acc = fmaf(Wih[j * H + h], in[h], acc);
        Sa += acc;
        Sq = fmaf(acc, acc, Sq);
        if (j < 20)       a60[j]      = acc;
        else if (j >= 40) a60[j - 20] = acc;
    }
    float mu  = Sa * (1.0f / H4);
    float var = fmaxf((Sq - Sa * mu) * (1.0f / (H4 - 1)), 0.f);
    float inv = 1.0f / (sqrtf(var) + EPSF);
    float c[H];
    float Sc = 0.f;
    #pragma unroll
    for (int h = 0; h < H; ++h) {
        float gv_i = fmaf((a60[h]      - mu) * inv, gi[h],      bi[h])      + bh[h];
        float gv_g = fmaf((a60[40 + h] - mu) * inv, gi[60 + h], bi[60 + h]) + bh[60 + h];
        c[h] = fast_sigm(gv_i) * fast_tanh(gv_g);
        Sc += c[h];
    }
    float mu2  = Sc * (1.0f / H);
    float var2 = 0.f;
    #pragma unroll
    for (int h = 0; h < H; ++h) { float d = c[h] - mu2; var2 = fmaf(d, d, var2); }
    float inv2 = 1.0f / (sqrtf(var2 * (1.0f / (H - 1))) + EPSF);
    #pragma unroll
    for (int h = 0; h < H; ++h) {
        float gv_o = fmaf((a60[20 + h] - mu) * inv, gi[40 + h], bi[40 + h]) + bh[40 + h];
        out[h] = fast_sigm(gv_o) * fast_tanh((c[h] - mu2) * inv2 * go[h] + bo[h]);
    }
}

__device__ __forceinline__ float eval_net_lds(float x, const float* w)
{
    float cur[H];
    {
        float t[H];
        float mu = 0.f;
        #pragma unroll
        for (int h = 0; h < H; ++h) {
            t[h] = fmaf(x, w[OFF_W1 + h], w[OFF_B1 + h]);
            mu += t[h];
        }
        mu *= (1.0f / H);
        float var = 0.f;
        #pragma unroll
        for (int h = 0; h < H; ++h) { float d = t[h] - mu; var = fmaf(d, d, var); }
        float inv = 1.0f / (sqrtf(var * (1.0f / (H - 1))) + EPSF);
        #pragma unroll
        for (int h = 0; h < H; ++h)
            cur[h] = fast_tanh((t[h] - mu) * inv * w[OFF_G1 + h] + w[OFF_BE1 + h]);
    }
    float nxt[H];
    lstm_layer_lds(cur, nxt, w + OFF_WIH0, w + OFF_GI0, w + OFF_BI0,
                   w + OFF_BH0, w + OFF_GO0, w + OFF_BO0);
    lstm_layer_lds(nxt, cur, w + OFF_WIH1, w + OFF_GI1, w + OFF_BI1,
                   w + OFF_BH1, w + OFF_GO1, w + OFF_BO1);
    float r = w[OFF_BOUT];
    #pragma unroll
    for (int h = 0; h < H; ++h) r = fmaf(cur[h], w[OFF_WOUT + h], r);
    return r;
}

__global__ void __launch_bounds__(256, 1)
direct_kernel(const float* __restrict__ x, float* __restrict__ out,
              int n, EVAL_PARAMS)
{
    __shared__ float w[NW];
    stage_weights(w, threadIdx.x, 256, EVAL_ARGS);
    int i = blockIdx.x * blockDim.x + threadIdx.x;
    if (i < n)
        out[i] = eval_net_lds(x[i], w);
}

extern "C" void kernel_launch(void* const* d_in, const int* in_sizes, int n_in,
                              void* d_out, int out_size, void* d_ws, size_t ws_size,
                              hipStream_t stream) {
    const float* x    = (const float*)d_in[0];
    const float* W1   = (const float*)d_in[1];
    const float* b1   = (const float*)d_in[2];
    const float* g1   = (const float*)d_in[3];
    const float* be1  = (const float*)d_in[4];
    const float* Wih0 = (const float*)d_in[5];
    // d_in[6] = Whh0 (dead: hx==0)
    const float* gi0  = (const float*)d_in[7];
    const float* bi0  = (const float*)d_in[8];
    // d_in[9] = gh0 (dead)
    const float* bh0  = (const float*)d_in[10];
    const float* go0  = (const float*)d_in[11];
    const float* bo0  = (const float*)d_in[12];
    const float* Wih1 = (const float*)d_in[13];
    // d_in[14] = Whh1 (dead)
    const float* gi1  = (const float*)d_in[15];
    const float* bi1  = (const float*)d_in[16];
    // d_in[17] = gh1 (dead)
    const float* bh1  = (const float*)d_in[18];
    const float* go1  = (const float*)d_in[19];
    const float* bo1  = (const float*)d_in[20];
    const float* Wout = (const float*)d_in[21];
    const float* bout = (const float*)d_in[22];

    float* out = (float*)d_out;
    int n = in_sizes[0];

    const int   NTAB  = 1024;          // intervals; 16 coefs KB -> L1-resident
    const float LO    = -8.0f, HIv = 8.0f;
    const float hstep = (HIv - LO) / (float)NTAB;

    const size_t coef_bytes = (size_t)NTAB * sizeof(f32x4);       // 16 KB

    if (ws_size >= coef_bytes) {
        f32x4* coef = (f32x4*)d_ws;
        build_coef_kernel<<<NTAB / 64, BQ_THREADS, 0, stream>>>(coef, LO, hstep,
                                                                EVAL_ARGS);
        int want = (n / 4 + 255) / 256;
        int lblocks = want < 2048 ? want : 2048;   // grid-stride cap (G11)
        lookup_cubic_kernel<<<lblocks, 256, 0, stream>>>(x, out, coef, n, LO,
                                                         HIv, 1.0f / hstep, NTAB);
    } else {
        int blocks = (n + 255) / 256;
        direct_kernel<<<blocks, 256, 0, stream>>>(x, out, n, EVAL_ARGS);
    }
}

// Round 8
// 129.237 us; speedup vs baseline: 2.2642x; 1.0336x over previous
//
#include <hip/hip_runtime.h>
#include <math.h>

#define H   20
#define H4  80
#define EPSF 1e-5f

typedef float f32x4 __attribute__((ext_vector_type(4)));

// LDS weight-block layout (floats). All float4-aligned offsets.
#define OFF_W1    0
#define OFF_B1    20
#define OFF_G1    40
#define OFF_BE1   60
#define OFF_WIH0  80
#define OFF_GI0   1680
#define OFF_BI0   1760
#define OFF_BH0   1840
#define OFF_GO0   1920
#define OFF_BO0   1940
#define OFF_WIH1  1960
#define OFF_GI1   3560
#define OFF_BI1   3640
#define OFF_BH1   3720
#define OFF_GO1   3800
#define OFF_BO1   3820
#define OFF_WOUT  3840
#define OFF_BOUT  3860
#define NW        3861

__device__ __forceinline__ float fast_sigm(float v) {
    return 1.0f / (1.0f + __expf(-v));
}
__device__ __forceinline__ float fast_tanh(float v) {
    return 2.0f / (1.0f + __expf(-2.0f * v)) - 1.0f;
}

// Sum across an aligned 4-lane quad (lanes q, q^1, q^2, q^3).
__device__ __forceinline__ float qsum(float v) {
    v += __shfl_xor(v, 1);
    v += __shfl_xor(v, 2);
    return v;
}

#define EVAL_PARAMS \
    const float* __restrict__ W1,   const float* __restrict__ b1,   \
    const float* __restrict__ g1,   const float* __restrict__ be1,  \
    const float* __restrict__ Wih0, const float* __restrict__ gi0,  \
    const float* __restrict__ bi0,  const float* __restrict__ bh0,  \
    const float* __restrict__ go0,  const float* __restrict__ bo0,  \
    const float* __restrict__ Wih1, const float* __restrict__ gi1,  \
    const float* __restrict__ bi1,  const float* __restrict__ bh1,  \
    const float* __restrict__ go1,  const float* __restrict__ bo1,  \
    const float* __restrict__ Wout, const float* __restrict__ bout
#define EVAL_ARGS W1, b1, g1, be1, Wih0, gi0, bi0, bh0, go0, bo0, \
                  Wih1, gi1, bi1, bh1, go1, bo1, Wout, bout

// Cooperative copy of all weights into LDS. Big matrices as float4
// (hipMalloc buffers are >=256B aligned; LDS offsets are float4-aligned).
__device__ __forceinline__ void stage_weights(float* w, int tid, int nthr,
                                              EVAL_PARAMS)
{
    f32x4* wv = reinterpret_cast<f32x4*>(w);
    const f32x4* a0 = reinterpret_cast<const f32x4*>(Wih0);
    const f32x4* a1 = reinterpret_cast<const f32x4*>(Wih1);
    for (int i = tid; i < 400; i += nthr) wv[OFF_WIH0 / 4 + i] = a0[i];
    for (int i = tid; i < 400; i += nthr) wv[OFF_WIH1 / 4 + i] = a1[i];
    #define CPY(OFFC, SRC, LEN)                                   \
        for (int i = tid; i < (LEN); i += nthr) w[(OFFC) + i] = (SRC)[i];
    CPY(OFF_W1,   W1,   20)   CPY(OFF_B1,   b1,   20)
    CPY(OFF_G1,   g1,   20)   CPY(OFF_BE1,  be1,  20)
    CPY(OFF_GI0,  gi0,  80)   CPY(OFF_BI0,  bi0,  80)
    CPY(OFF_BH0,  bh0,  80)   CPY(OFF_GO0,  go0,  20)
    CPY(OFF_BO0,  bo0,  20)   CPY(OFF_GI1,  gi1,  80)
    CPY(OFF_BI1,  bi1,  80)   CPY(OFF_BH1,  bh1,  80)
    CPY(OFF_GO1,  go1,  20)   CPY(OFF_BO1,  bo1,  20)
    CPY(OFF_WOUT, Wout, 20)   CPY(OFF_BOUT, bout, 1)
    #undef CPY
    __syncthreads();
}

// ---- Quad-parallel evaluation: 4 lanes cooperate on ONE sample ----
// Gate rows i=h, o=40+h, g=60+h are all == h (mod 4): lane q owns
// h in {q, q+4, ..., q+16} for all per-h gate math; only LN moments and the
// final dot need qsum (2x shfl_xor). Weight rows (20 floats, 16B-aligned)
// are read as 5x ds_read_b128; within a wave all 16 quads read the SAME
// address at each step (only q differs) -> 4 distinct addrs -> LDS broadcast.
__device__ float eval_quad(float x, const float* w, int q, int lane)
{
    int qb = lane & ~3;     // quad base lane (for shfl broadcast)
    const f32x4* wv = reinterpret_cast<const f32x4*>(w);

    // stage 1: LN(x*W1 + b1) -> tanh ; lane q owns h = q+4m
    float t5[5], cur5[5];
    #pragma unroll
    for (int m = 0; m < 5; ++m)
        t5[m] = fmaf(x, w[OFF_W1 + q + 4 * m], w[OFF_B1 + q + 4 * m]);
    float S = 0.f;
    #pragma unroll
    for (int m = 0; m < 5; ++m) S += t5[m];
    S = qsum(S);
    float mu = S * (1.0f / H);
    float V = 0.f;
    #pragma unroll
    for (int m = 0; m < 5; ++m) { float d = t5[m] - mu; V = fmaf(d, d, V); }
    V = qsum(V);
    float inv = 1.0f / (sqrtf(V * (1.0f / (H - 1))) + EPSF);
    #pragma unroll
    for (int m = 0; m < 5; ++m)
        cur5[m] = fast_tanh((t5[m] - mu) * inv * w[OFF_G1 + q + 4 * m]
                            + w[OFF_BE1 + q + 4 * m]);

    // two LN-LSTM layers
    #pragma unroll
    for (int layer = 0; layer < 2; ++layer) {
        const int wih4 = (layer ? OFF_WIH1 : OFF_WIH0) / 4;
        const float* gi = w + (layer ? OFF_GI1 : OFF_GI0);
        const float* bi = w + (layer ? OFF_BI1 : OFF_BI0);
        const float* bh = w + (layer ? OFF_BH1 : OFF_BH0);
        const float* go = w + (layer ? OFF_GO1 : OFF_GO0);
        const float* bo = w + (layer ? OFF_BO1 : OFF_BO0);

        // broadcast the quad-distributed input vector into all 4 lanes
        float in20[20];
        #pragma unroll
        for (int m = 0; m < 5; ++m) {
            #pragma unroll
            for (int qq = 0; qq < 4; ++qq)
                in20[4 * m + qq] = __shfl(cur5[m], qb + qq, 64);
        }

        // matvec: lane q computes rows r = q+4k, k=0..19 (20 of 80 rows)
        // row base in float4s: wih4 + 5q + 20k
        float a20[20];
        #pragma unroll
        for (int k = 0; k < 20; ++k) {
            int rb4 = wih4 + 5 * q + 20 * k;
            float acc = 0.f;
            #pragma unroll
            for (int c = 0; c < 5; ++c) {
                f32x4 wc = wv[rb4 + c];
                acc = fmaf(wc.x, in20[4 * c],     acc);
                acc = fmaf(wc.y, in20[4 * c + 1], acc);
                acc = fmaf(wc.z, in20[4 * c + 2], acc);
                acc = fmaf(wc.w, in20[4 * c + 3], acc);
            }
            a20[k] = acc;
        }
        // LN moments over all 80 rows (two-pass, ddof=1)
        float Sa = 0.f;
        #pragma unroll
        for (int k = 0; k < 20; ++k) Sa += a20[k];
        Sa = qsum(Sa);
        float mug = Sa * (1.0f / H4);
        float Vg = 0.f;
        #pragma unroll
        for (int k = 0; k < 20; ++k) { float d = a20[k] - mug; Vg = fmaf(d, d, Vg); }
        Vg = qsum(Vg);
        float invg = 1.0f / (sqrtf(Vg * (1.0f / (H4 - 1))) + EPSF);

        // c = sigm(i)*tanh(g): i rows k=0..4 (r=h), g rows k=15..19 (r=60+h)
        float c5[5];
        float Sc = 0.f;
        #pragma unroll
        for (int m = 0; m < 5; ++m) {
            int ri = q + 4 * m;          // i row (= h)
            int rg = 60 + q + 4 * m;     // g row
            float gv_i = fmaf((a20[m]      - mug) * invg, gi[ri], bi[ri]) + bh[ri];
            float gv_g = fmaf((a20[15 + m] - mug) * invg, gi[rg], bi[rg]) + bh[rg];
            c5[m] = fast_sigm(gv_i) * fast_tanh(gv_g);
            Sc += c5[m];
        }
        Sc = qsum(Sc);
        float mu2 = Sc * (1.0f / H);
        float V2 = 0.f;
        #pragma unroll
        for (int m = 0; m < 5; ++m) { float d = c5[m] - mu2; V2 = fmaf(d, d, V2); }
        V2 = qsum(V2);
        float inv2 = 1.0f / (sqrtf(V2 * (1.0f / (H - 1))) + EPSF);

        // out = sigm(o)*tanh(LN(c)): o rows k=10..14 (r=40+h)
        #pragma unroll
        for (int m = 0; m < 5; ++m) {
            int h  = q + 4 * m;
            int ro = 40 + h;
            float gv_o = fmaf((a20[10 + m] - mug) * invg, gi[ro], bi[ro]) + bh[ro];
            cur5[m] = fast_sigm(gv_o)
                    * fast_tanh((c5[m] - mu2) * inv2 * go[h] + bo[h]);
        }
    }

    // final dot: out @ Wout + bout
    float rp = 0.f;
    #pragma unroll
    for (int m = 0; m < 5; ++m)
        rp = fmaf(cur5[m], w[OFF_WOUT + q + 4 * m], rp);
    rp = qsum(rp);
    return rp + w[OFF_BOUT];
}

// ---- Fused builder: samples (quad-parallel) + Catmull-Rom coef pack ----
// NTAB=1024 intervals over [-8,8]; 16 blocks x 320 threads (80 quads).
// Block b: quads g=0..66 compute samples j = 64b+g (sample j = F(lo+(j-1)h),
// 3-sample overlap with next block); threads 0..63 then emit coef[64b+t].
#define BQ_THREADS 320
__global__ void __launch_bounds__(BQ_THREADS, 1)
build_coef_kernel(f32x4* __restrict__ coef, float lo, float hstep, EVAL_PARAMS)
{
    __shared__ __align__(16) float w[NW];
    __shared__ float s_samp[67];
    stage_weights(w, threadIdx.x, BQ_THREADS, EVAL_ARGS);

    int g    = threadIdx.x >> 2;
    int q    = threadIdx.x & 3;
    int lane = threadIdx.x & 63;
    int s0   = blockIdx.x * 64;
    if (g < 67) {
        int j = s0 + g;                          // 0..1026
        float xv = lo + hstep * (float)(j - 1);  // ghost point at j=0
        float v  = eval_quad(xv, w, q, lane);
        if (q == 0) s_samp[g] = v;
    }
    __syncthreads();

    int t = threadIdx.x;
    if (t < 64) {
        float p0 = s_samp[t];
        float p1 = s_samp[t + 1];
        float p2 = s_samp[t + 2];
        float p3 = s_samp[t + 3];
        f32x4 c;
        c.x = p1;
        c.y = 0.5f * (p2 - p0);
        c.z = p0 - 2.5f * p1 + 2.0f * p2 - 0.5f * p3;
        c.w = 1.5f * (p1 - p2) + 0.5f * (p3 - p0);
        coef[s0 + t] = c;
    }
}

// out[i] = cubic(coef, clamp(x[i])). Coef table staged in LDS (16 KB; at
// 8 blocks/CU = 128 KB <= 160 KB, occupancy preserved) so gathers are
// predictable ds_read_b128 instead of the L1 gather path. Non-temporal on
// the x/out streams.
#define NTAB_C 1024
__global__ void __launch_bounds__(256)
lookup_cubic_kernel(const float* __restrict__ x, float* __restrict__ out,
                    const f32x4* __restrict__ coef, int n,
                    float lo, float hi, float inv_h)
{
    __shared__ f32x4 s_coef[NTAB_C];
    for (int i = threadIdx.x; i < NTAB_C; i += 256)
        s_coef[i] = coef[i];
    __syncthreads();

    int n4 = n >> 2;
    int stride = gridDim.x * blockDim.x;
    const f32x4* x4 = reinterpret_cast<const f32x4*>(x);
    f32x4* o4 = reinterpret_cast<f32x4*>(out);
    for (int i = blockIdx.x * blockDim.x + threadIdx.x; i < n4; i += stride) {
        f32x4 v = __builtin_nontemporal_load(x4 + i);
        f32x4 r;
        #pragma unroll
        for (int k = 0; k < 4; ++k) {
            float xx = fminf(fmaxf(v[k], lo), hi);
            float tt = (xx - lo) * inv_h;
            int idx  = (int)tt;
            idx = idx < (NTAB_C - 1) ? idx : (NTAB_C - 1);
            float fr = tt - (float)idx;
            f32x4 cf = s_coef[idx];
            r[k] = fmaf(fmaf(fmaf(cf.w, fr, cf.z), fr, cf.y), fr, cf.x);
        }
        __builtin_nontemporal_store(r, o4 + i);
    }
    int rem = n & 3;
    if (blockIdx.x == 0 && (int)threadIdx.x < rem) {
        int e = n4 * 4 + threadIdx.x;
        float xx = fminf(fmaxf(x[e], lo), hi);
        float tt = (xx - lo) * inv_h;
        int idx  = (int)tt;
        idx = idx < (NTAB_C - 1) ? idx : (NTAB_C - 1);
        float fr = tt - (float)idx;
        f32x4 cf = s_coef[idx];
        out[e] = fmaf(fmaf(fmaf(cf.w, fr, cf.z), fr, cf.y), fr, cf.x);
    }
}

// ---- Fallback: direct per-element eval (only if ws can't hold 16 KB) ----
__device__ __forceinline__ void lstm_layer_lds(
    const float in[H], float out[H],
    const float* Wih, const float* gi, const float* bi, const float* bh,
    const float* go,  const float* bo)
{
    float a60[60];
    float Sa = 0.f, Sq = 0.f;
    #pragma unroll
    for (int j = 0; j < H4; ++j) {
        float acc = 0.f;
        #pragma unroll
        for (int h = 0; h < H; ++h)
            acc = fmaf(Wih[j * H + h], in[h], acc);
        Sa += acc;
        Sq = fmaf(acc, acc, Sq);
        if (j < 20)       a60[j]      = acc;
        else if (j >= 40) a60[j - 20] = acc;
    }
    float mu  = Sa * (1.0f / H4);
    float var = fmaxf((Sq - Sa * mu) * (1.0f / (H4 - 1)), 0.f);
    float inv = 1.0f / (sqrtf(var) + EPSF);
    float c[H];
    float Sc = 0.f;
    #pragma unroll
    for (int h = 0; h < H; ++h) {
        float gv_i = fmaf((a60[h]      - mu) * inv, gi[h],      bi[h])      + bh[h];
        float gv_g = fmaf((a60[40 + h] - mu) * inv, gi[60 + h], bi[60 + h]) + bh[60 + h];
        c[h] = fast_sigm(gv_i) * fast_tanh(gv_g);
        Sc += c[h];
    }
    float mu2  = Sc * (1.0f / H);
    float var2 = 0.f;
    #pragma unroll
    for (int h = 0; h < H; ++h) { float d = c[h] - mu2; var2 = fmaf(d, d, var2); }
    float inv2 = 1.0f / (sqrtf(var2 * (1.0f / (H - 1))) + EPSF);
    #pragma unroll
    for (int h = 0; h < H; ++h) {
        float gv_o = fmaf((a60[20 + h] - mu) * inv, gi[40 + h], bi[40 + h]) + bh[40 + h];
        out[h] = fast_sigm(gv_o) * fast_tanh((c[h] - mu2) * inv2 * go[h] + bo[h]);
    }
}

__device__ __forceinline__ float eval_net_lds(float x, const float* w)
{
    float cur[H];
    {
        float t[H];
        float mu = 0.f;
        #pragma unroll
        for (int h = 0; h < H; ++h) {
            t[h] = fmaf(x, w[OFF_W1 + h], w[OFF_B1 + h]);
            mu += t[h];
        }
        mu *= (1.0f / H);
        float var = 0.f;
        #pragma unroll
        for (int h = 0; h < H; ++h) { float d = t[h] - mu; var = fmaf(d, d, var); }
        float inv = 1.0f / (sqrtf(var * (1.0f / (H - 1))) + EPSF);
        #pragma unroll
        for (int h = 0; h < H; ++h)
            cur[h] = fast_tanh((t[h] - mu) * inv * w[OFF_G1 + h] + w[OFF_BE1 + h]);
    }
    float nxt[H];
    lstm_layer_lds(cur, nxt, w + OFF_WIH0, w + OFF_GI0, w + OFF_BI0,
                   w + OFF_BH0, w + OFF_GO0, w + OFF_BO0);
    lstm_layer_lds(nxt, cur, w + OFF_WIH1, w + OFF_GI1, w + OFF_BI1,
                   w + OFF_BH1, w + OFF_GO1, w + OFF_BO1);
    float r = w[OFF_BOUT];
    #pragma unroll
    for (int h = 0; h < H; ++h) r = fmaf(cur[h], w[OFF_WOUT + h], r);
    return r;
}

__global__ void __launch_bounds__(256, 1)
direct_kernel(const float* __restrict__ x, float* __restrict__ out,
              int n, EVAL_PARAMS)
{
    __shared__ __align__(16) float w[NW];
    stage_weights(w, threadIdx.x, 256, EVAL_ARGS);
    int i = blockIdx.x * blockDim.x + threadIdx.x;
    if (i < n)
        out[i] = eval_net_lds(x[i], w);
}

extern "C" void kernel_launch(void* const* d_in, const int* in_sizes, int n_in,
                              void* d_out, int out_size, void* d_ws, size_t ws_size,
                              hipStream_t stream) {
    const float* x    = (const float*)d_in[0];
    const float* W1   = (const float*)d_in[1];
    const float* b1   = (const float*)d_in[2];
    const float* g1   = (const float*)d_in[3];
    const float* be1  = (const float*)d_in[4];
    const float* Wih0 = (const float*)d_in[5];
    // d_in[6] = Whh0 (dead: hx==0)
    const float* gi0  = (const float*)d_in[7];
    const float* bi0  = (const float*)d_in[8];
    // d_in[9] = gh0 (dead)
    const float* bh0  = (const float*)d_in[10];
    const float* go0  = (const float*)d_in[11];
    const float* bo0  = (const float*)d_in[12];
    const float* Wih1 = (const float*)d_in[13];
    // d_in[14] = Whh1 (dead)
    const float* gi1  = (const float*)d_in[15];
    const float* bi1  = (const float*)d_in[16];
    // d_in[17] = gh1 (dead)
    const float* bh1  = (const float*)d_in[18];
    const float* go1  = (const float*)d_in[19];
    const float* bo1  = (const float*)d_in[20];
    const float* Wout = (const float*)d_in[21];
    const float* bout = (const float*)d_in[22];

    float* out = (float*)d_out;
    int n = in_sizes[0];

    const int   NTAB  = NTAB_C;        // 1024 intervals; 16 KB coef table
    const float LO    = -8.0f, HIv = 8.0f;
    const float hstep = (HIv - LO) / (float)NTAB;

    const size_t coef_bytes = (size_t)NTAB * sizeof(f32x4);       // 16 KB

    if (ws_size >= coef_bytes) {
        f32x4* coef = (f32x4*)d_ws;
        build_coef_kernel<<<NTAB / 64, BQ_THREADS, 0, stream>>>(coef, LO, hstep,
                                                                EVAL_ARGS);
        int want = (n / 4 + 255) / 256;
        int lblocks = want < 2048 ? want : 2048;   // grid-stride cap (G11)
        lookup_cubic_kernel<<<lblocks, 256, 0, stream>>>(x, out, coef, n, LO,
                                                         HIv, 1.0f / hstep);
    } else {
        int blocks = (n + 255) / 256;
        direct_kernel<<<blocks, 256, 0, stream>>>(x, out, n, EVAL_ARGS);
    }
}

// Round 9
// 128.571 us; speedup vs baseline: 2.2759x; 1.0052x over previous
//
#include <hip/hip_runtime.h>
#include <math.h>

#define H   20
#define H4  80
#define EPSF 1e-5f

typedef float f32x4 __attribute__((ext_vector_type(4)));

// LDS weight-block layout (floats). All float4-aligned offsets.
#define OFF_W1    0
#define OFF_B1    20
#define OFF_G1    40
#define OFF_BE1   60
#define OFF_WIH0  80
#define OFF_GI0   1680
#define OFF_BI0   1760
#define OFF_BH0   1840
#define OFF_GO0   1920
#define OFF_BO0   1940
#define OFF_WIH1  1960
#define OFF_GI1   3560
#define OFF_BI1   3640
#define OFF_BH1   3720
#define OFF_GO1   3800
#define OFF_BO1   3820
#define OFF_WOUT  3840
#define OFF_BOUT  3860
#define NW        3861

#define NTAB_C 1024

__device__ __forceinline__ float fast_sigm(float v) {
    return 1.0f / (1.0f + __expf(-v));
}
__device__ __forceinline__ float fast_tanh(float v) {
    return 2.0f / (1.0f + __expf(-2.0f * v)) - 1.0f;
}

// Sum across an aligned 4-lane quad (lanes q, q^1, q^2, q^3).
__device__ __forceinline__ float qsum(float v) {
    v += __shfl_xor(v, 1);
    v += __shfl_xor(v, 2);
    return v;
}

#define EVAL_PARAMS \
    const float* __restrict__ W1,   const float* __restrict__ b1,   \
    const float* __restrict__ g1,   const float* __restrict__ be1,  \
    const float* __restrict__ Wih0, const float* __restrict__ gi0,  \
    const float* __restrict__ bi0,  const float* __restrict__ bh0,  \
    const float* __restrict__ go0,  const float* __restrict__ bo0,  \
    const float* __restrict__ Wih1, const float* __restrict__ gi1,  \
    const float* __restrict__ bi1,  const float* __restrict__ bh1,  \
    const float* __restrict__ go1,  const float* __restrict__ bo1,  \
    const float* __restrict__ Wout, const float* __restrict__ bout
#define EVAL_ARGS W1, b1, g1, be1, Wih0, gi0, bi0, bh0, go0, bo0, \
                  Wih1, gi1, bi1, bh1, go1, bo1, Wout, bout

// Cooperative copy of all weights into LDS. Big matrices as float4.
__device__ __forceinline__ void stage_weights(float* w, int tid, int nthr,
                                              EVAL_PARAMS)
{
    f32x4* wv = reinterpret_cast<f32x4*>(w);
    const f32x4* a0 = reinterpret_cast<const f32x4*>(Wih0);
    const f32x4* a1 = reinterpret_cast<const f32x4*>(Wih1);
    for (int i = tid; i < 400; i += nthr) wv[OFF_WIH0 / 4 + i] = a0[i];
    for (int i = tid; i < 400; i += nthr) wv[OFF_WIH1 / 4 + i] = a1[i];
    #define CPY(OFFC, SRC, LEN)                                   \
        for (int i = tid; i < (LEN); i += nthr) w[(OFFC) + i] = (SRC)[i];
    CPY(OFF_W1,   W1,   20)   CPY(OFF_B1,   b1,   20)
    CPY(OFF_G1,   g1,   20)   CPY(OFF_BE1,  be1,  20)
    CPY(OFF_GI0,  gi0,  80)   CPY(OFF_BI0,  bi0,  80)
    CPY(OFF_BH0,  bh0,  80)   CPY(OFF_GO0,  go0,  20)
    CPY(OFF_BO0,  bo0,  20)   CPY(OFF_GI1,  gi1,  80)
    CPY(OFF_BI1,  bi1,  80)   CPY(OFF_BH1,  bh1,  80)
    CPY(OFF_GO1,  go1,  20)   CPY(OFF_BO1,  bo1,  20)
    CPY(OFF_WOUT, Wout, 20)   CPY(OFF_BOUT, bout, 1)
    #undef CPY
    __syncthreads();
}

// ---- Quad-parallel evaluation: 4 lanes cooperate on ONE sample ----
// Gate rows i=h, o=40+h, g=60+h are all == h (mod 4): lane q owns
// h in {q, q+4, ..., q+16} for all per-h gate math; only LN moments and the
// final dot need qsum (2x shfl_xor). Weight rows read as 5x ds_read_b128
// (wave-uniform addr per step modulo q -> 4 distinct addrs -> LDS broadcast).
__device__ float eval_quad(float x, const float* w, int q, int lane)
{
    int qb = lane & ~3;     // quad base lane (for shfl broadcast)
    const f32x4* wv = reinterpret_cast<const f32x4*>(w);

    // stage 1: LN(x*W1 + b1) -> tanh ; lane q owns h = q+4m
    float t5[5], cur5[5];
    #pragma unroll
    for (int m = 0; m < 5; ++m)
        t5[m] = fmaf(x, w[OFF_W1 + q + 4 * m], w[OFF_B1 + q + 4 * m]);
    float S = 0.f;
    #pragma unroll
    for (int m = 0; m < 5; ++m) S += t5[m];
    S = qsum(S);
    float mu = S * (1.0f / H);
    float V = 0.f;
    #pragma unroll
    for (int m = 0; m < 5; ++m) { float d = t5[m] - mu; V = fmaf(d, d, V); }
    V = qsum(V);
    float inv = 1.0f / (sqrtf(V * (1.0f / (H - 1))) + EPSF);
    #pragma unroll
    for (int m = 0; m < 5; ++m)
        cur5[m] = fast_tanh((t5[m] - mu) * inv * w[OFF_G1 + q + 4 * m]
                            + w[OFF_BE1 + q + 4 * m]);

    // two LN-LSTM layers
    #pragma unroll
    for (int layer = 0; layer < 2; ++layer) {
        const int wih4 = (layer ? OFF_WIH1 : OFF_WIH0) / 4;
        const float* gi = w + (layer ? OFF_GI1 : OFF_GI0);
        const float* bi = w + (layer ? OFF_BI1 : OFF_BI0);
        const float* bh = w + (layer ? OFF_BH1 : OFF_BH0);
        const float* go = w + (layer ? OFF_GO1 : OFF_GO0);
        const float* bo = w + (layer ? OFF_BO1 : OFF_BO0);

        // broadcast the quad-distributed input vector into all 4 lanes
        float in20[20];
        #pragma unroll
        for (int m = 0; m < 5; ++m) {
            #pragma unroll
            for (int qq = 0; qq < 4; ++qq)
                in20[4 * m + qq] = __shfl(cur5[m], qb + qq, 64);
        }

        // matvec: lane q computes rows r = q+4k, k=0..19 (20 of 80 rows)
        float a20[20];
        #pragma unroll
        for (int k = 0; k < 20; ++k) {
            int rb4 = wih4 + 5 * q + 20 * k;
            float acc = 0.f;
            #pragma unroll
            for (int c = 0; c < 5; ++c) {
                f32x4 wc = wv[rb4 + c];
                acc = fmaf(wc.x, in20[4 * c],     acc);
                acc = fmaf(wc.y, in20[4 * c + 1], acc);
                acc = fmaf(wc.z, in20[4 * c + 2], acc);
                acc = fmaf(wc.w, in20[4 * c + 3], acc);
            }
            a20[k] = acc;
        }
        // LN moments over all 80 rows (two-pass, ddof=1)
        float Sa = 0.f;
        #pragma unroll
        for (int k = 0; k < 20; ++k) Sa += a20[k];
        Sa = qsum(Sa);
        float mug = Sa * (1.0f / H4);
        float Vg = 0.f;
        #pragma unroll
        for (int k = 0; k < 20; ++k) { float d = a20[k] - mug; Vg = fmaf(d, d, Vg); }
        Vg = qsum(Vg);
        float invg = 1.0f / (sqrtf(Vg * (1.0f / (H4 - 1))) + EPSF);

        // c = sigm(i)*tanh(g): i rows k=0..4 (r=h), g rows k=15..19 (r=60+h)
        float c5[5];
        float Sc = 0.f;
        #pragma unroll
        for (int m = 0; m < 5; ++m) {
            int ri = q + 4 * m;
            int rg = 60 + q + 4 * m;
            float gv_i = fmaf((a20[m]      - mug) * invg, gi[ri], bi[ri]) + bh[ri];
            float gv_g = fmaf((a20[15 + m] - mug) * invg, gi[rg], bi[rg]) + bh[rg];
            c5[m] = fast_sigm(gv_i) * fast_tanh(gv_g);
            Sc += c5[m];
        }
        Sc = qsum(Sc);
        float mu2 = Sc * (1.0f / H);
        float V2 = 0.f;
        #pragma unroll
        for (int m = 0; m < 5; ++m) { float d = c5[m] - mu2; V2 = fmaf(d, d, V2); }
        V2 = qsum(V2);
        float inv2 = 1.0f / (sqrtf(V2 * (1.0f / (H - 1))) + EPSF);

        // out = sigm(o)*tanh(LN(c)): o rows k=10..14 (r=40+h)
        #pragma unroll
        for (int m = 0; m < 5; ++m) {
            int h  = q + 4 * m;
            int ro = 40 + h;
            float gv_o = fmaf((a20[10 + m] - mug) * invg, gi[ro], bi[ro]) + bh[ro];
            cur5[m] = fast_sigm(gv_o)
                    * fast_tanh((c5[m] - mu2) * inv2 * go[h] + bo[h]);
        }
    }

    // final dot: out @ Wout + bout
    float rp = 0.f;
    #pragma unroll
    for (int m = 0; m < 5; ++m)
        rp = fmaf(cur5[m], w[OFF_WOUT + q + 4 * m], rp);
    rp = qsum(rp);
    return rp + w[OFF_BOUT];
}

// ---- Fused builder: samples (quad-parallel) + Catmull-Rom coef pack ----
// SoA coef output: cx|cy|cz|cw as 4 contiguous float[NTAB_C] arrays in ws.
// (SoA -> the lookup's random gathers become 4x b32 LDS reads ~2 lanes/bank,
// which is conflict-free (m136), instead of b128 ~8-way (2.9x serialized).)
#define BQ_THREADS 320
__global__ void __launch_bounds__(BQ_THREADS, 1)
build_coef_kernel(float* __restrict__ ctab,    // [4][NTAB_C] SoA
                  float lo, float hstep, EVAL_PARAMS)
{
    __shared__ __align__(16) float w[NW];
    __shared__ float s_samp[67];
    stage_weights(w, threadIdx.x, BQ_THREADS, EVAL_ARGS);

    int g    = threadIdx.x >> 2;
    int q    = threadIdx.x & 3;
    int lane = threadIdx.x & 63;
    int s0   = blockIdx.x * 64;
    if (g < 67) {
        int j = s0 + g;                          // 0..1026
        float xv = lo + hstep * (float)(j - 1);  // ghost point at j=0
        float v  = eval_quad(xv, w, q, lane);
        if (q == 0) s_samp[g] = v;
    }
    __syncthreads();

    int t = threadIdx.x;
    if (t < 64) {
        float p0 = s_samp[t];
        float p1 = s_samp[t + 1];
        float p2 = s_samp[t + 2];
        float p3 = s_samp[t + 3];
        int i = s0 + t;
        ctab[i]              = p1;                                     // cx
        ctab[NTAB_C + i]     = 0.5f * (p2 - p0);                       // cy
        ctab[2 * NTAB_C + i] = p0 - 2.5f * p1 + 2.0f * p2 - 0.5f * p3; // cz
        ctab[3 * NTAB_C + i] = 1.5f * (p1 - p2) + 0.5f * (p3 - p0);    // cw
    }
}

// out[i] = cubic at clamp(x[i]); SoA coef tables staged in LDS (16 KB).
__global__ void __launch_bounds__(256)
lookup_cubic_kernel(const float* __restrict__ x, float* __restrict__ out,
                    const float* __restrict__ ctab, int n,
                    float lo, float hi, float inv_h)
{
    __shared__ float s_cx[NTAB_C], s_cy[NTAB_C], s_cz[NTAB_C], s_cw[NTAB_C];
    for (int i = threadIdx.x; i < NTAB_C; i += 256) {
        s_cx[i] = ctab[i];
        s_cy[i] = ctab[NTAB_C + i];
        s_cz[i] = ctab[2 * NTAB_C + i];
        s_cw[i] = ctab[3 * NTAB_C + i];
    }
    __syncthreads();

    int n4 = n >> 2;
    int stride = gridDim.x * blockDim.x;
    const f32x4* x4 = reinterpret_cast<const f32x4*>(x);
    f32x4* o4 = reinterpret_cast<f32x4*>(out);
    for (int i = blockIdx.x * blockDim.x + threadIdx.x; i < n4; i += stride) {
        f32x4 v = __builtin_nontemporal_load(x4 + i);
        f32x4 r;
        #pragma unroll
        for (int k = 0; k < 4; ++k) {
            float xx = fminf(fmaxf(v[k], lo), hi);
            float tt = (xx - lo) * inv_h;
            int idx  = (int)tt;
            idx = idx < (NTAB_C - 1) ? idx : (NTAB_C - 1);
            float fr = tt - (float)idx;
            float cx = s_cx[idx], cy = s_cy[idx], cz = s_cz[idx], cw = s_cw[idx];
            r[k] = fmaf(fmaf(fmaf(cw, fr, cz), fr, cy), fr, cx);
        }
        __builtin_nontemporal_store(r, o4 + i);
    }
    int rem = n & 3;
    if (blockIdx.x == 0 && (int)threadIdx.x < rem) {
        int e = n4 * 4 + threadIdx.x;
        float xx = fminf(fmaxf(x[e], lo), hi);
        float tt = (xx - lo) * inv_h;
        int idx  = (int)tt;
        idx = idx < (NTAB_C - 1) ? idx : (NTAB_C - 1);
        float fr = tt - (float)idx;
        out[e] = fmaf(fmaf(fmaf(s_cw[idx], fr, s_cz[idx]), fr, s_cy[idx]),
                      fr, s_cx[idx]);
    }
}

// ---- Fallback: direct per-element eval (only if ws can't hold 16 KB) ----
__device__ __forceinline__ void lstm_layer_lds(
    const float in[H], float out[H],
    const float* Wih, const float* gi, const float* bi, const float* bh,
    const float* go,  const float* bo)
{
    float a60[60];
    float Sa = 0.f, Sq = 0.f;
    #pragma unroll
    for (int j = 0; j < H4; ++j) {
        float acc = 0.f;
        #pragma unroll
        for (int h = 0; h < H; ++h)
            acc = fmaf(Wih[j * H + h], in[h], acc);
        Sa += acc;
        Sq = fmaf(acc, acc, Sq);
        if (j < 20)       a60[j]      = acc;
        else if (j >= 40) a60[j - 20] = acc;
    }
    float mu  = Sa * (1.0f / H4);
    float var = fmaxf((Sq - Sa * mu) * (1.0f / (H4 - 1)), 0.f);
    float inv = 1.0f / (sqrtf(var) + EPSF);
    float c[H];
    float Sc = 0.f;
    #pragma unroll
    for (int h = 0; h < H; ++h) {
        float gv_i = fmaf((a60[h]      - mu) * inv, gi[h],      bi[h])      + bh[h];
        float gv_g = fmaf((a60[40 + h] - mu) * inv, gi[60 + h], bi[60 + h]) + bh[60 + h];
        c[h] = fast_sigm(gv_i) * fast_tanh(gv_g);
        Sc += c[h];
    }
    float mu2  = Sc * (1.0f / H);
    float var2 = 0.f;
    #pragma unroll
    for (int h = 0; h < H; ++h) { float d = c[h] - mu2; var2 = fmaf(d, d, var2); }
    float inv2 = 1.0f / (sqrtf(var2 * (1.0f / (H - 1))) + EPSF);
    #pragma unroll
    for (int h = 0; h < H; ++h) {
        float gv_o = fmaf((a60[20 + h] - mu) * inv, gi[40 + h], bi[40 + h]) + bh[40 + h];
        out[h] = fast_sigm(gv_o) * fast_tanh((c[h] - mu2) * inv2 * go[h] + bo[h]);
    }
}

__device__ __forceinline__ float eval_net_lds(float x, const float* w)
{
    float cur[H];
    {
        float t[H];
        float mu = 0.f;
        #pragma unroll
        for (int h = 0; h < H; ++h) {
            t[h] = fmaf(x, w[OFF_W1 + h], w[OFF_B1 + h]);
            mu += t[h];
        }
        mu *= (1.0f / H);
        float var = 0.f;
        #pragma unroll
        for (int h = 0; h < H; ++h) { float d = t[h] - mu; var = fmaf(d, d, var); }
        float inv = 1.0f / (sqrtf(var * (1.0f / (H - 1))) + EPSF);
        #pragma unroll
        for (int h = 0; h < H; ++h)
            cur[h] = fast_tanh((t[h] - mu) * inv * w[OFF_G1 + h] + w[OFF_BE1 + h]);
    }
    float nxt[H];
    lstm_layer_lds(cur, nxt, w + OFF_WIH0, w + OFF_GI0, w + OFF_BI0,
                   w + OFF_BH0, w + OFF_GO0, w + OFF_BO0);
    lstm_layer_lds(nxt, cur, w + OFF_WIH1, w + OFF_GI1, w + OFF_BI1,
                   w + OFF_BH1, w + OFF_GO1, w + OFF_BO1);
    float r = w[OFF_BOUT];
    #pragma unroll
    for (int h = 0; h < H; ++h) r = fmaf(cur[h], w[OFF_WOUT + h], r);
    return r;
}

__global__ void __launch_bounds__(256, 1)
direct_kernel(const float* __restrict__ x, float* __restrict__ out,
              int n, EVAL_PARAMS)
{
    __shared__ __align__(16) float w[NW];
    stage_weights(w, threadIdx.x, 256, EVAL_ARGS);
    int i = blockIdx.x * blockDim.x + threadIdx.x;
    if (i < n)
        out[i] = eval_net_lds(x[i], w);
}

extern "C" void kernel_launch(void* const* d_in, const int* in_sizes, int n_in,
                              void* d_out, int out_size, void* d_ws, size_t ws_size,
                              hipStream_t stream) {
    const float* x    = (const float*)d_in[0];
    const float* W1   = (const float*)d_in[1];
    const float* b1   = (const float*)d_in[2];
    const float* g1   = (const float*)d_in[3];
    const float* be1  = (const float*)d_in[4];
    const float* Wih0 = (const float*)d_in[5];
    // d_in[6] = Whh0 (dead: hx==0)
    const float* gi0  = (const float*)d_in[7];
    const float* bi0  = (const float*)d_in[8];
    // d_in[9] = gh0 (dead)
    const float* bh0  = (const float*)d_in[10];
    const float* go0  = (const float*)d_in[11];
    const float* bo0  = (const float*)d_in[12];
    const float* Wih1 = (const float*)d_in[13];
    // d_in[14] = Whh1 (dead)
    const float* gi1  = (const float*)d_in[15];
    const float* bi1  = (const float*)d_in[16];
    // d_in[17] = gh1 (dead)
    const float* bh1  = (const float*)d_in[18];
    const float* go1  = (const float*)d_in[19];
    const float* bo1  = (const float*)d_in[20];
    const float* Wout = (const float*)d_in[21];
    const float* bout = (const float*)d_in[22];

    float* out = (float*)d_out;
    int n = in_sizes[0];

    const float LO    = -8.0f, HIv = 8.0f;
    const float hstep = (HIv - LO) / (float)NTAB_C;

    const size_t coef_bytes = (size_t)4 * NTAB_C * sizeof(float);  // 16 KB SoA

    if (ws_size >= coef_bytes) {
        float* ctab = (float*)d_ws;
        build_coef_kernel<<<NTAB_C / 64, BQ_THREADS, 0, stream>>>(ctab, LO,
                                                                  hstep, EVAL_ARGS);
        int want = (n / 4 + 255) / 256;
        int lblocks = want < 2048 ? want : 2048;   // grid-stride cap (G11)
        lookup_cubic_kernel<<<lblocks, 256, 0, stream>>>(x, out, ctab, n, LO,
                                                         HIv, 1.0f / hstep);
    } else {
        int blocks = (n + 255) / 256;
        direct_kernel<<<blocks, 256, 0, stream>>>(x, out, n, EVAL_ARGS);
    }
}